// Round 1
// baseline (1329.447 us; speedup 1.0000x reference)
//
#include <hip/hip_runtime.h>
#include <hip/hip_bf16.h>

typedef __attribute__((ext_vector_type(8))) short  short8;
typedef __attribute__((ext_vector_type(4))) int    int4v;
typedef __attribute__((ext_vector_type(4))) float  float4v;

#define B_   256
#define T_   200
#define H_   256
#define GB   16
#define NBLK 16
#define FWD_ 64
#define S_H    5.0f
#define INV_SH 25.4f            // 127/S_H

__device__ __forceinline__ float sigf(float x)     { return 1.f / (1.f + __expf(-x)); }
__device__ __forceinline__ float tanhfast(float x) { return 2.f / (1.f + __expf(-2.f * x)) - 1.f; }
__device__ __forceinline__ unsigned bf16rne(float x) {
  unsigned u = __float_as_uint(x);
  return (u + 0x7FFFu + ((u >> 16) & 1u)) >> 16;
}
__device__ __forceinline__ int q8(float v) {
  float r = rintf(v);
  r = fminf(fmaxf(r, -127.f), 127.f);
  return (int)r;
}

// ---------- pack stage 1: per-ROW max-abs of Whh (+ scale, + Wih col17) ----------
__global__ void pack_scales(const float* __restrict__ Whh, const float* __restrict__ Wih,
                            float* __restrict__ Mraw, float* __restrict__ SCL4,
                            float* __restrict__ WIH17) {
  __shared__ float red[4];
  int orow = blockIdx.x, tt = threadIdx.x;
  float m = fabsf(Whh[orow * 256 + tt]);
  #pragma unroll
  for (int off = 32; off; off >>= 1) m = fmaxf(m, __shfl_xor(m, off));
  if ((tt & 63) == 0) red[tt >> 6] = m;
  __syncthreads();
  if (tt == 0) {
    m = fmaxf(fmaxf(red[0], red[1]), fmaxf(red[2], red[3]));
    m = fmaxf(m, 1e-20f);
    Mraw[orow] = m;
    // SCL4 as float4[d]: component g = scale of row (d + g*256).
    // Pre-divided by 254: gate q is merged exactly as qc = 254*a1 + a2.
    SCL4[(orow & 255) * 4 + (orow >> 8)] = m * (S_H / 16129.f / 254.f);
    // f32 Wih column 17 (zp coefficient) for the rank-1 zp term
    WIH17[(orow & 255) * 4 + (orow >> 8)] = Wih[orow * 18 + 17];
  }
}

// ---------- pack stage 2: fragments (unchanged layouts) ----------
__global__ void pack_frags(const float* __restrict__ Wih, const float* __restrict__ Whh,
                           const float* __restrict__ b,   const float* __restrict__ W1,
                           const float* __restrict__ Mraw,
                           uint4* __restrict__ PA8, uint4* __restrict__ W1Pg,
                           uint4* __restrict__ WU) {
  int tid = blockIdx.x * blockDim.x + threadIdx.x;
  if (tid < 16384) {
    int mt = tid >> 8, rem = tid & 255, kt = rem >> 6, l = rem & 63;
    int r = mt * 16 + (l & 15), d = r >> 2, g = r & 3, orow = d + g * 256;
    int kb = kt * 64 + (l >> 4) * 16;
    float qs = 127.f / Mraw[orow];
    unsigned w[4];
    #pragma unroll
    for (int jj = 0; jj < 4; ++jj) {
      unsigned acc = 0;
      #pragma unroll
      for (int s = 0; s < 4; ++s) {
        int q = q8(Whh[orow * 256 + kb + jj * 4 + s] * qs);
        acc |= ((unsigned)(q & 255)) << (8 * s);
      }
      w[jj] = acc;
    }
    PA8[tid] = make_uint4(w[0], w[1], w[2], w[3]);
    return;
  }
  int t2 = tid - 16384;
  if (t2 >= 0 && t2 < 2048) {
    int l = t2 & 63, kt = (t2 >> 6) & 7, mt = t2 >> 9;
    int row = mt * 16 + (l & 15), kb = kt * 32 + (l >> 4) * 8;
    unsigned w[4];
    #pragma unroll
    for (int jj = 0; jj < 4; ++jj) {
      unsigned lo = bf16rne(W1[row * 256 + kb + jj * 2 + 0]);
      unsigned hi = bf16rne(W1[row * 256 + kb + jj * 2 + 1]);
      w[jj] = lo | (hi << 16);
    }
    W1Pg[t2] = make_uint4(w[0], w[1], w[2], w[3]);
    return;
  }
  int t3 = t2 - 2048;
  if (t3 >= 0 && t3 < 4096) {
    int mt = t3 >> 6, l = t3 & 63;
    int r = mt * 16 + (l & 15), d = r >> 2, g = r & 3, orow = d + g * 256;
    unsigned w[4];
    #pragma unroll
    for (int jj = 0; jj < 4; ++jj) {
      unsigned lohi[2];
      #pragma unroll
      for (int s = 0; s < 2; ++s) {
        int k = (l >> 4) * 8 + jj * 2 + s;
        float v = (k == 0) ? b[orow]
                : (k <= 18) ? Wih[orow * 18 + (k - 1)]
                : (k == 19) ? Wih[orow * 18 + 17] : 0.f;
        lohi[s] = bf16rne(v);
      }
      w[jj] = lohi[0] | (lohi[1] << 16);
    }
    WU[t3] = make_uint4(w[0], w[1], w[2], w[3]);
  }
}

// One block = 16 batch elems, 16 waves, 1 CU. 2 barriers per step:
//   phase A : act/quant from PG regs (+ f32 rank-1 zp term), write h frags,
//             waves 12-15 stage u(t+1)
//   bar1
//   overlap : ALL waves issue next step's gate MFMAs (i8 two-term + bf16 u)
//             -> pgf regs;  waves 0-3 concurrently FF + partial-delta -> pslot
//   bar2
//   combine : every thread sums pslot redundantly, zp_r stays in a register
// All LDS single-buffered (bar2 separates each read from the next write).
__global__ __launch_bounds__(1024, 4) void lstm_kernel(
    const float* __restrict__ z, const float* __restrict__ x, const float* __restrict__ h0,
    const int4v* __restrict__ PA8, const short8* __restrict__ WUg,
    const uint4* __restrict__ W1Pg, const float* __restrict__ SCL4g,
    const float* __restrict__ W17g,
    const float* __restrict__ b1g, const float* __restrict__ W2,
    const float* __restrict__ b2, float* __restrict__ out) {
  __shared__ __align__(16) char   BF1s[4096];     // h term-1 i8 frags
  __shared__ __align__(16) char   BF2s[4096];     // h term-2 i8 frags (residual)
  __shared__ __align__(16) ushort HBs[4096];      // h bf16 frags (FF)
  __shared__ __align__(16) uint4  UF[64];         // u bf16 frags (zp slots stay 0)
  __shared__ __align__(16) uint4  W1ls[2048];     // W1 bf16 A-frags, 32 KB
  __shared__ __align__(16) float4 scl_lds[256];   // per-row W scales / 254
  __shared__ __align__(16) float4 wih17_lds[256]; // f32 Wih col 17 per (d, gate)
  __shared__ float pslot[64];                     // per-wave delta partials [4][16]
  __shared__ float b1_lds[64], w2_lds[64];

  const int t = threadIdx.x, l = t & 63, wid = t >> 6;
  const int bcol = l & 15, lk = l >> 4;
  const int b0 = blockIdx.x * GB;

  // ---- static register preloads: Whh int8 A-frags (64 regs, AGPR-resident) ----
  int4v wA[16];
  #pragma unroll
  for (int i = 0; i < 4; ++i)
    #pragma unroll
    for (int kt = 0; kt < 4; ++kt)
      wA[i * 4 + kt] = PA8[((wid * 4 + i) * 4 + kt) * 64 + l];
  const float b2v = b2[0];

  W1ls[t]        = W1Pg[t];
  W1ls[t + 1024] = W1Pg[t + 1024];
  if (t < 256) scl_lds[t]   = ((const float4*)SCL4g)[t];
  if (t < 256) wih17_lds[t] = ((const float4*)W17g)[t];
  if (t < 64) { b1_lds[t] = b1g[t]; w2_lds[t] = W2[t]; }
  #pragma unroll
  for (int q = 0; q < 4; ++q) {   // h0 -> BF1/BF2 (two-term, clamped q8: h0 unbounded)
    int idx = q * 1024 + t, d = idx >> 4, bb = idx & 15;
    float hv = h0[(b0 + bb) * H_ + d];
    int t1 = q8(hv * INV_SH);
    float rr = hv * INV_SH - (float)t1;
    int t2i = q8(rr * 254.f);
    int addr = ((d >> 6) * 64 + ((d >> 4) & 3) * 16 + bb) * 16 + (d & 15);
    BF1s[addr] = (char)t1;
    BF2s[addr] = (char)t2i;
  }

  auto stage_u = [&](int tn) {    // t in [768,1024): one dword each, full UF cover
    int st = t - 768;
    int bb = (st >> 2) & 15, lk2 = st >> 6, jj = st & 3;
    int k0 = lk2 * 8 + jj * 2, k1 = k0 + 1;
    float v0 = (k0 == 0) ? 1.f
             : (k0 == 1) ? z[(b0 + bb) * T_ + tn]
             : (k0 <= 17) ? x[((b0 + bb) * T_ + tn) * 16 + (k0 - 2)] : 0.f;
    float v1 = (k1 == 1) ? z[(b0 + bb) * T_ + tn]
             : (k1 <= 17) ? x[((b0 + bb) * T_ + tn) * 16 + (k1 - 2)] : 0.f;
    ((unsigned*)UF)[(lk2 * 16 + bb) * 4 + jj] = bf16rne(v0) | (bf16rne(v1) << 16);
  };

  float4v pgf[4];                 // partial gates for the upcoming step (16 regs)

  auto compute_pg = [&]() {
    short8 wuR[4];                // step-invariant Wih/bias frags: load early,
    #pragma unroll                // L2 latency hides under the i8 MFMA chain
    for (int i = 0; i < 4; ++i) wuR[i] = WUg[(wid * 4 + i) * 64 + l];
    short8 uf = ((const short8*)UF)[l];
    int4v a1[4], a2[4];
    #pragma unroll
    for (int i = 0; i < 4; ++i) { a1[i] = (int4v){0,0,0,0}; a2[i] = (int4v){0,0,0,0}; }
    #pragma unroll
    for (int kt = 0; kt < 4; ++kt) {
      int4v bq1 = *(const int4v*)&BF1s[(kt * 64 + l) * 16];
      int4v bq2 = *(const int4v*)&BF2s[(kt * 64 + l) * 16];
      #pragma unroll
      for (int i = 0; i < 4; ++i) {
        a1[i] = __builtin_amdgcn_mfma_i32_16x16x64_i8(wA[i * 4 + kt], bq1, a1[i], 0, 0, 0);
        a2[i] = __builtin_amdgcn_mfma_i32_16x16x64_i8(wA[i * 4 + kt], bq2, a2[i], 0, 0, 0);
      }
    }
    #pragma unroll
    for (int i = 0; i < 4; ++i) {
      float4v f = __builtin_amdgcn_mfma_f32_16x16x32_bf16(wuR[i], uf,
                      (float4v){0.f, 0.f, 0.f, 0.f}, 0, 0, 0);
      float4 sc = scl_lds[wid * 16 + i * 4 + lk];
      // exact two-term merge: qc = 254*a1 + a2 (|qc| <= 1.05e9, no overflow)
      pgf[i][0] = fmaf((float)(a1[i][0] * 254 + a2[i][0]), sc.x, f[0]);
      pgf[i][1] = fmaf((float)(a1[i][1] * 254 + a2[i][1]), sc.y, f[1]);
      pgf[i][2] = fmaf((float)(a1[i][2] * 254 + a2[i][2]), sc.z, f[2]);
      pgf[i][3] = fmaf((float)(a1[i][3] * 254 + a2[i][3]), sc.w, f[3]);
    }
  };

  if (t >= 768) stage_u(0);
  float c_r[4] = {0.f, 0.f, 0.f, 0.f}, h_r[4] = {0.f, 0.f, 0.f, 0.f};
  float zp_r = 0.f;
  __syncthreads();
  compute_pg();                   // PG for step 0 from h0 frags + u_0
  __syncthreads();

  for (int ts = 0; ts < T_; ++ts) {
    // ---- phase A: g = pgf + Wih17*zp (f32), activations, quant, h frags ----
    #pragma unroll
    for (int i = 0; i < 4; ++i) {
      const int d = wid * 16 + i * 4 + lk;
      float4 w17 = wih17_lds[d];
      float g0 = fmaf(w17.x, zp_r, pgf[i][0]);
      float g1 = fmaf(w17.y, zp_r, pgf[i][1]);
      float g2 = fmaf(w17.z, zp_r, pgf[i][2]);
      float g3 = fmaf(w17.w, zp_r, pgf[i][3]);
      float ig = sigf(g0), fg = sigf(g1), gc = tanhfast(g2), og = sigf(g3);
      float cc = fmaf(fg, c_r[i], ig * gc);
      c_r[i] = cc;
      float hh = og * tanhfast(cc);
      h_r[i] = hh;
      float v = hh * INV_SH;            // |h|<1 -> |v|<=25.4, no clamps needed
      float t1f = rintf(v);
      int   t1  = (int)t1f;
      float rr  = v - t1f;              // in [-0.5,0.5] -> t2 in [-127,127]
      int   t2i = (int)rintf(rr * 254.f);
      int addr = ((d >> 6) * 64 + ((d >> 4) & 3) * 16 + bcol) * 16 + (d & 15);
      BF1s[addr] = (char)t1;
      BF2s[addr] = (char)t2i;
      HBs[((d >> 5) * 64 + ((d >> 3) & 3) * 16 + bcol) * 8 + (d & 7)] = (ushort)bf16rne(hh);
    }
    if (t >= 768 && ts + 1 < T_) stage_u(ts + 1);
    __syncthreads();   // (1) h frags + u(t+1) visible

    // ---- overlap: next-step PG MFMAs (all waves) || FF+partial-delta (waves 0-3) ----
    if (ts + 1 < T_) compute_pg();
    if (wid < 4) {
      float4v fa = (float4v){0.f, 0.f, 0.f, 0.f};
      const short* w1s = (const short*)W1ls;
      #pragma unroll
      for (int kt = 0; kt < 8; ++kt) {
        short8 bf = *(const short8*)&HBs[(kt * 64 + l) * 8];
        short8 wf = *(const short8*)&w1s[((wid * 8 + kt) * 64 + l) * 8];
        fa = __builtin_amdgcn_mfma_f32_16x16x32_bf16(wf, bf, fa, 0, 0, 0);
      }
      float s = 0.f;
      #pragma unroll
      for (int r = 0; r < 4; ++r) {
        int j = wid * 16 + lk * 4 + r;
        s = fmaf(w2_lds[j], fmaxf(fa[r] + b1_lds[j], 0.f), s);
      }
      s += __shfl_xor(s, 16);          // reduce over lk: lanes with same bcol
      s += __shfl_xor(s, 32);
      if (l < 16) pslot[wid * 16 + l] = s;
    }
    __syncthreads();   // (2) pslot ready

    // ---- combine: redundant per-thread delta; zp stays in a register ----
    {
      float sdel = (pslot[bcol] + pslot[16 + bcol]) + (pslot[32 + bcol] + pslot[48 + bcol]);
      float delta = fmaxf(sdel + b2v, 0.f);
      zp_r += delta;
      if (wid == 15 && l < 16) out[(b0 + l) * T_ + ts] = zp_r;
    }
  }

  #pragma unroll
  for (int i = 0; i < 4; ++i) {
    int d = wid * 16 + i * 4 + lk;
    out[B_ * T_ + (b0 + bcol) * H_ + d]            = h_r[i];
    out[B_ * T_ + B_ * H_ + (b0 + bcol) * H_ + d]  = c_r[i];
  }
}

extern "C" void kernel_launch(void* const* d_in, const int* in_sizes, int n_in,
                              void* d_out, int out_size, void* d_ws, size_t ws_size,
                              hipStream_t stream) {
  const float* z   = (const float*)d_in[0];
  const float* x   = (const float*)d_in[1];
  const float* h0  = (const float*)d_in[2];
  const float* Wih = (const float*)d_in[3];
  const float* Whh = (const float*)d_in[4];
  const float* b   = (const float*)d_in[5];
  const float* W1  = (const float*)d_in[6];
  const float* b1  = (const float*)d_in[7];
  const float* W2  = (const float*)d_in[8];
  const float* b2  = (const float*)d_in[9];
  float* out = (float*)d_out;

  char* ws = (char*)d_ws;
  uint4* PA8   = (uint4*)(ws);             // 16384*16 = 262144 B
  uint4* W1Pg  = (uint4*)(ws + 262144);    //  2048*16 =  32768 B
  uint4* WU    = (uint4*)(ws + 294912);    //  4096*16 =  65536 B
  float* SCL4  = (float*)(ws + 360448);    //  1024*4  =   4096 B
  float* Mraw  = (float*)(ws + 364544);    //  1024*4  =   4096 B
  float* WIH17 = (float*)(ws + 368640);    //  1024*4  =   4096 B

  pack_scales<<<1024, 256, 0, stream>>>(Whh, Wih, Mraw, SCL4, WIH17);
  int total = 16384 + 2048 + 4096;
  pack_frags<<<(total + 255) / 256, 256, 0, stream>>>(Wih, Whh, b, W1, Mraw,
                                                      PA8, W1Pg, WU);
  lstm_kernel<<<NBLK, 1024, 0, stream>>>(z, x, h0, (const int4v*)PA8, (const short8*)WU,
                                         W1Pg, SCL4, WIH17, b1, W2, b2, out);
}

// Round 2
// 1296.932 us; speedup vs baseline: 1.0251x; 1.0251x over previous
//
#include <hip/hip_runtime.h>
#include <hip/hip_bf16.h>

typedef __attribute__((ext_vector_type(8))) short  short8;
typedef __attribute__((ext_vector_type(4))) int    int4v;
typedef __attribute__((ext_vector_type(4))) float  float4v;

#define B_   256
#define T_   200
#define H_   256
#define GB   16
#define NBLK 16
#define FWD_ 64
#define S_H    5.0f
#define INV_SH 25.4f            // 127/S_H

__device__ __forceinline__ float sigf(float x)     { return 1.f / (1.f + __expf(-x)); }
__device__ __forceinline__ float tanhfast(float x) { return 2.f / (1.f + __expf(-2.f * x)) - 1.f; }
__device__ __forceinline__ unsigned bf16rne(float x) {
  unsigned u = __float_as_uint(x);
  return (u + 0x7FFFu + ((u >> 16) & 1u)) >> 16;
}
__device__ __forceinline__ int q8(float v) {
  float r = rintf(v);
  r = fminf(fmaxf(r, -127.f), 127.f);
  return (int)r;
}

// ---------- pack stage 1: per-ROW max-abs of Whh (+ scale, + Wih col17) ----------
__global__ void pack_scales(const float* __restrict__ Whh, const float* __restrict__ Wih,
                            float* __restrict__ Mraw, float* __restrict__ SCL4,
                            float* __restrict__ WIH17) {
  __shared__ float red[4];
  int orow = blockIdx.x, tt = threadIdx.x;
  float m = fabsf(Whh[orow * 256 + tt]);
  #pragma unroll
  for (int off = 32; off; off >>= 1) m = fmaxf(m, __shfl_xor(m, off));
  if ((tt & 63) == 0) red[tt >> 6] = m;
  __syncthreads();
  if (tt == 0) {
    m = fmaxf(fmaxf(red[0], red[1]), fmaxf(red[2], red[3]));
    m = fmaxf(m, 1e-20f);
    Mraw[orow] = m;
    // SCL4 as float4[d]: component g = scale of row (d + g*256).
    // Pre-divided by 254: gate q is merged exactly as qc = 254*a1 + a2.
    SCL4[(orow & 255) * 4 + (orow >> 8)] = m * (S_H / 16129.f / 254.f);
    // f32 Wih column 17 (zp coefficient) for the rank-1 zp term
    WIH17[(orow & 255) * 4 + (orow >> 8)] = Wih[orow * 18 + 17];
  }
}

// ---------- pack stage 2: fragments (unchanged layouts) ----------
__global__ void pack_frags(const float* __restrict__ Wih, const float* __restrict__ Whh,
                           const float* __restrict__ b,   const float* __restrict__ W1,
                           const float* __restrict__ Mraw,
                           uint4* __restrict__ PA8, uint4* __restrict__ W1Pg,
                           uint4* __restrict__ WU) {
  int tid = blockIdx.x * blockDim.x + threadIdx.x;
  if (tid < 16384) {
    int mt = tid >> 8, rem = tid & 255, kt = rem >> 6, l = rem & 63;
    int r = mt * 16 + (l & 15), d = r >> 2, g = r & 3, orow = d + g * 256;
    int kb = kt * 64 + (l >> 4) * 16;
    float qs = 127.f / Mraw[orow];
    unsigned w[4];
    #pragma unroll
    for (int jj = 0; jj < 4; ++jj) {
      unsigned acc = 0;
      #pragma unroll
      for (int s = 0; s < 4; ++s) {
        int q = q8(Whh[orow * 256 + kb + jj * 4 + s] * qs);
        acc |= ((unsigned)(q & 255)) << (8 * s);
      }
      w[jj] = acc;
    }
    PA8[tid] = make_uint4(w[0], w[1], w[2], w[3]);
    return;
  }
  int t2 = tid - 16384;
  if (t2 >= 0 && t2 < 2048) {
    int l = t2 & 63, kt = (t2 >> 6) & 7, mt = t2 >> 9;
    int row = mt * 16 + (l & 15), kb = kt * 32 + (l >> 4) * 8;
    unsigned w[4];
    #pragma unroll
    for (int jj = 0; jj < 4; ++jj) {
      unsigned lo = bf16rne(W1[row * 256 + kb + jj * 2 + 0]);
      unsigned hi = bf16rne(W1[row * 256 + kb + jj * 2 + 1]);
      w[jj] = lo | (hi << 16);
    }
    W1Pg[t2] = make_uint4(w[0], w[1], w[2], w[3]);
    return;
  }
  int t3 = t2 - 2048;
  if (t3 >= 0 && t3 < 4096) {
    int mt = t3 >> 6, l = t3 & 63;
    int r = mt * 16 + (l & 15), d = r >> 2, g = r & 3, orow = d + g * 256;
    unsigned w[4];
    #pragma unroll
    for (int jj = 0; jj < 4; ++jj) {
      unsigned lohi[2];
      #pragma unroll
      for (int s = 0; s < 2; ++s) {
        int k = (l >> 4) * 8 + jj * 2 + s;
        float v = (k == 0) ? b[orow]
                : (k <= 18) ? Wih[orow * 18 + (k - 1)]
                : (k == 19) ? Wih[orow * 18 + 17] : 0.f;
        lohi[s] = bf16rne(v);
      }
      w[jj] = lohi[0] | (lohi[1] << 16);
    }
    WU[t3] = make_uint4(w[0], w[1], w[2], w[3]);
  }
}

// One block = 16 batch elems, 16 waves, 1 CU. 2 barriers per step:
//   phase A : staging waves ds_write u(ts+1) from prefetch regs; all waves
//             activations from pgf (+ f32 rank-1 zp), write h frags
//   bar1
//   overlap : staging waves ISSUE global loads u(ts+2) (latency hides under
//             MFMAs); all waves compute_pg (pp-split, 16 accums at a time);
//             waves 0-3 additionally FF + partial-delta -> pslot (transposed)
//   bar2
//   combine : one ds_read_b128 of pslot, redundant per-thread delta; zp_r
//             stays in a register
// All weights on-chip after prologue: wA in AGPRs, WU/W1/scales in LDS.
__global__ __launch_bounds__(1024, 4) void lstm_kernel(
    const float* __restrict__ z, const float* __restrict__ x, const float* __restrict__ h0,
    const int4v* __restrict__ PA8, const uint4* __restrict__ WUg,
    const uint4* __restrict__ W1Pg, const float* __restrict__ SCL4g,
    const float* __restrict__ W17g,
    const float* __restrict__ b1g, const float* __restrict__ W2,
    const float* __restrict__ b2, float* __restrict__ out) {
  __shared__ __align__(16) char   BF1s[4096];     // h term-1 i8 frags
  __shared__ __align__(16) char   BF2s[4096];     // h term-2 i8 frags (residual)
  __shared__ __align__(16) ushort HBs[4096];      // h bf16 frags (FF)
  __shared__ __align__(16) uint4  UF[64];         // u bf16 frags (zp slots stay 0)
  __shared__ __align__(16) uint4  W1ls[2048];     // W1 bf16 A-frags, 32 KB
  __shared__ __align__(16) uint4  WUls[4096];     // Wih/bias bf16 A-frags, 64 KB
  __shared__ __align__(16) float4 scl_lds[256];   // per-row W scales / 254
  __shared__ __align__(16) float4 wih17_lds[256]; // f32 Wih col 17 per (d, gate)
  __shared__ __align__(16) float  pslot[64];      // delta partials, TRANSPOSED [16][4]
  __shared__ float b1_lds[64], w2_lds[64];

  const int t = threadIdx.x, l = t & 63, wid = t >> 6;
  const int bcol = l & 15, lk = l >> 4;
  const int b0 = blockIdx.x * GB;

  // ---- static register preloads: Whh int8 A-frags (64 regs, AGPR-resident) ----
  int4v wA[16];
  #pragma unroll
  for (int i = 0; i < 4; ++i)
    #pragma unroll
    for (int kt = 0; kt < 4; ++kt)
      wA[i * 4 + kt] = PA8[((wid * 4 + i) * 4 + kt) * 64 + l];
  const float b2v = b2[0];

  W1ls[t]        = W1Pg[t];
  W1ls[t + 1024] = W1Pg[t + 1024];
  #pragma unroll
  for (int q = 0; q < 4; ++q) WUls[q * 1024 + t] = WUg[q * 1024 + t];
  if (t < 256) scl_lds[t]   = ((const float4*)SCL4g)[t];
  if (t < 256) wih17_lds[t] = ((const float4*)W17g)[t];
  if (t < 64) { b1_lds[t] = b1g[t]; w2_lds[t] = W2[t]; }
  #pragma unroll
  for (int q = 0; q < 4; ++q) {   // h0 -> BF1/BF2 (two-term, clamped q8: h0 unbounded)
    int idx = q * 1024 + t, d = idx >> 4, bb = idx & 15;
    float hv = h0[(b0 + bb) * H_ + d];
    int t1 = q8(hv * INV_SH);
    float rr = hv * INV_SH - (float)t1;
    int t2i = q8(rr * 254.f);
    int addr = ((d >> 6) * 64 + ((d >> 4) & 3) * 16 + bb) * 16 + (d & 15);
    BF1s[addr] = (char)t1;
    BF2s[addr] = (char)t2i;
  }

  // ---- u staging: loads issued one step early, held in 2 regs (T14) ----
  auto load_u = [&](int tn, float& v0, float& v1) {   // t in [768,1024)
    int st = t - 768;
    int bb = (st >> 2) & 15, lk2 = st >> 6, jj = st & 3;
    int k0 = lk2 * 8 + jj * 2, k1 = k0 + 1;
    const float* xb = &x[((b0 + bb) * T_ + tn) * 16];
    v0 = (k0 == 0) ? 1.f
       : (k0 == 1) ? z[(b0 + bb) * T_ + tn]
       : (k0 <= 17) ? xb[k0 - 2] : 0.f;
    v1 = (k1 == 1) ? z[(b0 + bb) * T_ + tn]
       : (k1 <= 17) ? xb[k1 - 2] : 0.f;
  };
  auto write_u = [&](float v0, float v1) {
    int st = t - 768;
    int bb = (st >> 2) & 15, lk2 = st >> 6, jj = st & 3;
    ((unsigned*)UF)[(lk2 * 16 + bb) * 4 + jj] = bf16rne(v0) | (bf16rne(v1) << 16);
  };

  float4v pgf[4];                 // partial gates for the upcoming step (16 regs)

  // pp-split: only 16 int accums + 8 wu regs live at a time (R0 register profile)
  auto compute_pg = [&]() {
    const short8* wuls = (const short8*)WUls;
    #pragma unroll
    for (int pp = 0; pp < 2; ++pp) {
      short8 wu0 = wuls[(wid * 4 + pp * 2 + 0) * 64 + l];
      short8 wu1 = wuls[(wid * 4 + pp * 2 + 1) * 64 + l];
      short8 uf  = ((const short8*)UF)[l];
      int4v a10 = {0,0,0,0}, a20 = {0,0,0,0}, a11 = {0,0,0,0}, a21 = {0,0,0,0};
      #pragma unroll
      for (int kt = 0; kt < 4; ++kt) {
        int4v bq1 = *(const int4v*)&BF1s[(kt * 64 + l) * 16];
        int4v bq2 = *(const int4v*)&BF2s[(kt * 64 + l) * 16];
        a10 = __builtin_amdgcn_mfma_i32_16x16x64_i8(wA[(pp * 2 + 0) * 4 + kt], bq1, a10, 0, 0, 0);
        a20 = __builtin_amdgcn_mfma_i32_16x16x64_i8(wA[(pp * 2 + 0) * 4 + kt], bq2, a20, 0, 0, 0);
        a11 = __builtin_amdgcn_mfma_i32_16x16x64_i8(wA[(pp * 2 + 1) * 4 + kt], bq1, a11, 0, 0, 0);
        a21 = __builtin_amdgcn_mfma_i32_16x16x64_i8(wA[(pp * 2 + 1) * 4 + kt], bq2, a21, 0, 0, 0);
      }
      float4v f0 = __builtin_amdgcn_mfma_f32_16x16x32_bf16(wu0, uf, (float4v){0.f,0.f,0.f,0.f}, 0, 0, 0);
      float4v f1 = __builtin_amdgcn_mfma_f32_16x16x32_bf16(wu1, uf, (float4v){0.f,0.f,0.f,0.f}, 0, 0, 0);
      #pragma unroll
      for (int ii = 0; ii < 2; ++ii) {
        int i = pp * 2 + ii;
        float4 sc = scl_lds[wid * 16 + i * 4 + lk];
        // exact two-term merge: qc = 254*a1 + a2 (|qc| <= 1.05e9, no overflow)
        pgf[i][0] = fmaf((float)((ii ? a11[0] : a10[0]) * 254 + (ii ? a21[0] : a20[0])), sc.x, (ii ? f1 : f0)[0]);
        pgf[i][1] = fmaf((float)((ii ? a11[1] : a10[1]) * 254 + (ii ? a21[1] : a20[1])), sc.y, (ii ? f1 : f0)[1]);
        pgf[i][2] = fmaf((float)((ii ? a11[2] : a10[2]) * 254 + (ii ? a21[2] : a20[2])), sc.z, (ii ? f1 : f0)[2]);
        pgf[i][3] = fmaf((float)((ii ? a11[3] : a10[3]) * 254 + (ii ? a21[3] : a20[3])), sc.w, (ii ? f1 : f0)[3]);
      }
    }
  };

  float ld0 = 0.f, ld1 = 0.f;
  if (t >= 768) {
    load_u(0, ld0, ld1);
    write_u(ld0, ld1);            // UF <- u(0)
    load_u(1, ld0, ld1);          // prefetch u(1) into regs
  }
  float c_r[4] = {0.f, 0.f, 0.f, 0.f}, h_r[4] = {0.f, 0.f, 0.f, 0.f};
  float zp_r = 0.f;
  __syncthreads();                // h0 frags + UF(0) + LDS weights visible
  compute_pg();                   // PG for step 0
  __syncthreads();

  for (int ts = 0; ts < T_; ++ts) {
    // ---- phase A: ds_write u(ts+1); g = pgf + Wih17*zp; act; quant; frags ----
    if (t >= 768) write_u(ld0, ld1);     // stale write at ts=T-1 is never read
    #pragma unroll
    for (int i = 0; i < 4; ++i) {
      const int d = wid * 16 + i * 4 + lk;
      float4 w17 = wih17_lds[d];
      float g0 = fmaf(w17.x, zp_r, pgf[i][0]);
      float g1 = fmaf(w17.y, zp_r, pgf[i][1]);
      float g2 = fmaf(w17.z, zp_r, pgf[i][2]);
      float g3 = fmaf(w17.w, zp_r, pgf[i][3]);
      float ig = sigf(g0), fg = sigf(g1), gc = tanhfast(g2), og = sigf(g3);
      float cc = fmaf(fg, c_r[i], ig * gc);
      c_r[i] = cc;
      float hh = og * tanhfast(cc);
      h_r[i] = hh;
      float v = hh * INV_SH;            // |h|<1 -> |v|<=25.4, no clamps needed
      float t1f = rintf(v);
      int   t1  = (int)t1f;
      float rr  = v - t1f;              // in [-0.5,0.5] -> t2 in [-127,127]
      int   t2i = (int)rintf(rr * 254.f);
      int addr = ((d >> 6) * 64 + ((d >> 4) & 3) * 16 + bcol) * 16 + (d & 15);
      BF1s[addr] = (char)t1;
      BF2s[addr] = (char)t2i;
      HBs[((d >> 5) * 64 + ((d >> 3) & 3) * 16 + bcol) * 8 + (d & 7)] = (ushort)bf16rne(hh);
    }
    __syncthreads();   // (1) h frags + u(ts+1) visible

    // ---- overlap: prefetch u(ts+2) || next-step PG MFMAs || FF (waves 0-3) ----
    if (t >= 768 && ts + 2 < T_) load_u(ts + 2, ld0, ld1);  // latency hides under MFMAs
    if (ts + 1 < T_) compute_pg();
    if (wid < 4) {
      float4v fa = (float4v){0.f, 0.f, 0.f, 0.f};
      const short* w1s = (const short*)W1ls;
      #pragma unroll
      for (int kt = 0; kt < 8; ++kt) {
        short8 bf = *(const short8*)&HBs[(kt * 64 + l) * 8];
        short8 wf = *(const short8*)&w1s[((wid * 8 + kt) * 64 + l) * 8];
        fa = __builtin_amdgcn_mfma_f32_16x16x32_bf16(wf, bf, fa, 0, 0, 0);
      }
      float s = 0.f;
      #pragma unroll
      for (int r = 0; r < 4; ++r) {
        int j = wid * 16 + lk * 4 + r;
        s = fmaf(w2_lds[j], fmaxf(fa[r] + b1_lds[j], 0.f), s);
      }
      s += __shfl_xor(s, 16);          // reduce over lk: lanes with same bcol
      s += __shfl_xor(s, 32);
      if (l < 16) pslot[l * 4 + wid] = s;   // transposed: [batch][wave]
    }
    __syncthreads();   // (2) pslot ready

    // ---- combine: one b128 read, redundant per-thread delta; zp in register ----
    {
      float4 ps = ((const float4*)pslot)[bcol];
      float delta = fmaxf((ps.x + ps.y) + (ps.z + ps.w) + b2v, 0.f);
      zp_r += delta;
      if (wid == 15 && l < 16) out[(b0 + l) * T_ + ts] = zp_r;
    }
  }

  #pragma unroll
  for (int i = 0; i < 4; ++i) {
    int d = wid * 16 + i * 4 + lk;
    out[B_ * T_ + (b0 + bcol) * H_ + d]            = h_r[i];
    out[B_ * T_ + B_ * H_ + (b0 + bcol) * H_ + d]  = c_r[i];
  }
}

extern "C" void kernel_launch(void* const* d_in, const int* in_sizes, int n_in,
                              void* d_out, int out_size, void* d_ws, size_t ws_size,
                              hipStream_t stream) {
  const float* z   = (const float*)d_in[0];
  const float* x   = (const float*)d_in[1];
  const float* h0  = (const float*)d_in[2];
  const float* Wih = (const float*)d_in[3];
  const float* Whh = (const float*)d_in[4];
  const float* b   = (const float*)d_in[5];
  const float* W1  = (const float*)d_in[6];
  const float* b1  = (const float*)d_in[7];
  const float* W2  = (const float*)d_in[8];
  const float* b2  = (const float*)d_in[9];
  float* out = (float*)d_out;

  char* ws = (char*)d_ws;
  uint4* PA8   = (uint4*)(ws);             // 16384*16 = 262144 B
  uint4* W1Pg  = (uint4*)(ws + 262144);    //  2048*16 =  32768 B
  uint4* WU    = (uint4*)(ws + 294912);    //  4096*16 =  65536 B
  float* SCL4  = (float*)(ws + 360448);    //  1024*4  =   4096 B
  float* Mraw  = (float*)(ws + 364544);    //  1024*4  =   4096 B
  float* WIH17 = (float*)(ws + 368640);    //  1024*4  =   4096 B

  pack_scales<<<1024, 256, 0, stream>>>(Whh, Wih, Mraw, SCL4, WIH17);
  int total = 16384 + 2048 + 4096;
  pack_frags<<<(total + 255) / 256, 256, 0, stream>>>(Wih, Whh, b, W1, Mraw,
                                                      PA8, W1Pg, WU);
  lstm_kernel<<<NBLK, 1024, 0, stream>>>(z, x, h0, (const int4v*)PA8, (const uint4*)WU,
                                         W1Pg, SCL4, WIH17, b1, W2, b2, out);
}

// Round 3
// 823.760 us; speedup vs baseline: 1.6139x; 1.5744x over previous
//
#include <hip/hip_runtime.h>
#include <hip/hip_bf16.h>

typedef __attribute__((ext_vector_type(8))) short  short8;
typedef __attribute__((ext_vector_type(4))) int    int4v;
typedef __attribute__((ext_vector_type(4))) float  float4v;

#define B_   256
#define T_   200
#define H_   256
#define GB   16
#define NBLK 16
#define FWD_ 64
#define S_H    5.0f
#define INV_SH 25.4f            // 127/S_H
#define NL2E  (-1.44269504f)    // -log2(e)   (sigmoid gates, pre-folded)
#define NL2E2 (-2.88539008f)    // -2*log2(e) (tanh gate, pre-folded)

__device__ __forceinline__ float sig2(float gp) {   // gp = -log2e * g
  return __builtin_amdgcn_rcpf(1.f + __builtin_amdgcn_exp2f(gp));
}
__device__ __forceinline__ float tanh2(float gp) {  // gp = -2log2e * g
  return fmaf(__builtin_amdgcn_rcpf(1.f + __builtin_amdgcn_exp2f(gp)), 2.f, -1.f);
}
__device__ __forceinline__ float tanhc(float c) {   // raw units
  return fmaf(__builtin_amdgcn_rcpf(1.f + __builtin_amdgcn_exp2f(c * NL2E2)), 2.f, -1.f);
}
__device__ __forceinline__ unsigned bf16rne(float x) {
  unsigned u = __float_as_uint(x);
  return (u + 0x7FFFu + ((u >> 16) & 1u)) >> 16;
}
__device__ __forceinline__ int q8(float v) {
  float r = rintf(v);
  r = fminf(fmaxf(r, -127.f), 127.f);
  return (int)r;
}

// ---------- pack stage 1: per-ROW max-abs of Whh (+ folded scale, Wih col17) ----------
__global__ void pack_scales(const float* __restrict__ Whh, const float* __restrict__ Wih,
                            float* __restrict__ Mraw, float* __restrict__ SCL4,
                            float* __restrict__ WIH17) {
  __shared__ float red[4];
  int orow = blockIdx.x, tt = threadIdx.x;
  float m = fabsf(Whh[orow * 256 + tt]);
  #pragma unroll
  for (int off = 32; off; off >>= 1) m = fmaxf(m, __shfl_xor(m, off));
  if ((tt & 63) == 0) red[tt >> 6] = m;
  __syncthreads();
  if (tt == 0) {
    m = fmaxf(fmaxf(red[0], red[1]), fmaxf(red[2], red[3]));
    m = fmaxf(m, 1e-20f);
    Mraw[orow] = m;
    float fac = ((orow >> 8) == 2) ? NL2E2 : NL2E;  // gate 2 = cell tanh
    // SCL4 as float4[d]: component g = scale of row (d + g*256).
    // /254 for exact two-term merge qc=254*a1+a2; *fac folds exp->exp2 + sign.
    SCL4[(orow & 255) * 4 + (orow >> 8)] = m * (S_H / 16129.f / 254.f) * fac;
    WIH17[(orow & 255) * 4 + (orow >> 8)] = Wih[orow * 18 + 17] * fac;
  }
}

// ---------- pack stage 2: fragments (WU folded by fac) ----------
__global__ void pack_frags(const float* __restrict__ Wih, const float* __restrict__ Whh,
                           const float* __restrict__ b,   const float* __restrict__ W1,
                           const float* __restrict__ Mraw,
                           uint4* __restrict__ PA8, uint4* __restrict__ W1Pg,
                           uint4* __restrict__ WU) {
  int tid = blockIdx.x * blockDim.x + threadIdx.x;
  if (tid < 16384) {
    int mt = tid >> 8, rem = tid & 255, kt = rem >> 6, l = rem & 63;
    int r = mt * 16 + (l & 15), d = r >> 2, g = r & 3, orow = d + g * 256;
    int kb = kt * 64 + (l >> 4) * 16;
    float qs = 127.f / Mraw[orow];
    unsigned w[4];
    #pragma unroll
    for (int jj = 0; jj < 4; ++jj) {
      unsigned acc = 0;
      #pragma unroll
      for (int s = 0; s < 4; ++s) {
        int q = q8(Whh[orow * 256 + kb + jj * 4 + s] * qs);
        acc |= ((unsigned)(q & 255)) << (8 * s);
      }
      w[jj] = acc;
    }
    PA8[tid] = make_uint4(w[0], w[1], w[2], w[3]);
    return;
  }
  int t2 = tid - 16384;
  if (t2 >= 0 && t2 < 2048) {
    int l = t2 & 63, kt = (t2 >> 6) & 7, mt = t2 >> 9;
    int row = mt * 16 + (l & 15), kb = kt * 32 + (l >> 4) * 8;
    unsigned w[4];
    #pragma unroll
    for (int jj = 0; jj < 4; ++jj) {
      unsigned lo = bf16rne(W1[row * 256 + kb + jj * 2 + 0]);
      unsigned hi = bf16rne(W1[row * 256 + kb + jj * 2 + 1]);
      w[jj] = lo | (hi << 16);
    }
    W1Pg[t2] = make_uint4(w[0], w[1], w[2], w[3]);
    return;
  }
  int t3 = t2 - 2048;
  if (t3 >= 0 && t3 < 4096) {
    int mt = t3 >> 6, l = t3 & 63;
    int r = mt * 16 + (l & 15), d = r >> 2, g = r & 3, orow = d + g * 256;
    float fac = (g == 2) ? NL2E2 : NL2E;
    unsigned w[4];
    #pragma unroll
    for (int jj = 0; jj < 4; ++jj) {
      unsigned lohi[2];
      #pragma unroll
      for (int s = 0; s < 2; ++s) {
        int k = (l >> 4) * 8 + jj * 2 + s;
        float v = (k == 0) ? b[orow]
                : (k <= 18) ? Wih[orow * 18 + (k - 1)]
                : (k == 19) ? Wih[orow * 18 + 17] : 0.f;
        lohi[s] = bf16rne(v * fac);
      }
      w[jj] = lohi[0] | (lohi[1] << 16);
    }
    WU[t3] = make_uint4(w[0], w[1], w[2], w[3]);
  }
}

// Issues PP's 16 i8 + 2 bf16 MFMAs, runs ACTS (independent VALU) under their
// latency, then merges into pgA/pgB. PB/PU/PP must be such that wA index is
// compile-time (PP literal at call site).
#define GATE_MFMA(PB, PU, PP, pgA, pgB, ...) do {                              \
    const short8* _wuls = (const short8*)WUls;                                 \
    short8 _uf  = ((const short8*)UF[(PU)])[l];                                \
    short8 _wuA = _wuls[(wid * 4 + (PP) * 2 + 0) * 64 + l];                    \
    short8 _wuB = _wuls[(wid * 4 + (PP) * 2 + 1) * 64 + l];                    \
    int4v _aA1 = {0,0,0,0}, _aA2 = {0,0,0,0};                                  \
    int4v _aB1 = {0,0,0,0}, _aB2 = {0,0,0,0};                                  \
    _Pragma("unroll")                                                          \
    for (int _kt = 0; _kt < 4; ++_kt) {                                        \
      int4v _bq1 = *(const int4v*)&BF1s[(PB)][(_kt * 64 + l) * 16];            \
      int4v _bq2 = *(const int4v*)&BF2s[(PB)][(_kt * 64 + l) * 16];            \
      _aA1 = __builtin_amdgcn_mfma_i32_16x16x64_i8(wA[((PP)*2+0)*4+_kt], _bq1, _aA1, 0,0,0); \
      _aA2 = __builtin_amdgcn_mfma_i32_16x16x64_i8(wA[((PP)*2+0)*4+_kt], _bq2, _aA2, 0,0,0); \
      _aB1 = __builtin_amdgcn_mfma_i32_16x16x64_i8(wA[((PP)*2+1)*4+_kt], _bq1, _aB1, 0,0,0); \
      _aB2 = __builtin_amdgcn_mfma_i32_16x16x64_i8(wA[((PP)*2+1)*4+_kt], _bq2, _aB2, 0,0,0); \
    }                                                                          \
    float4v _fA = __builtin_amdgcn_mfma_f32_16x16x32_bf16(_wuA, _uf, (float4v){0.f,0.f,0.f,0.f}, 0,0,0); \
    float4v _fB = __builtin_amdgcn_mfma_f32_16x16x32_bf16(_wuB, _uf, (float4v){0.f,0.f,0.f,0.f}, 0,0,0); \
    __VA_ARGS__                                                                \
    float4 _scA = scl_lds[wid * 16 + ((PP)*2+0) * 4 + lk];                     \
    float4 _scB = scl_lds[wid * 16 + ((PP)*2+1) * 4 + lk];                     \
    (pgA)[0] = fmaf((float)(_aA1[0]*254 + _aA2[0]), _scA.x, _fA[0]);           \
    (pgA)[1] = fmaf((float)(_aA1[1]*254 + _aA2[1]), _scA.y, _fA[1]);           \
    (pgA)[2] = fmaf((float)(_aA1[2]*254 + _aA2[2]), _scA.z, _fA[2]);           \
    (pgA)[3] = fmaf((float)(_aA1[3]*254 + _aA2[3]), _scA.w, _fA[3]);           \
    (pgB)[0] = fmaf((float)(_aB1[0]*254 + _aB2[0]), _scB.x, _fB[0]);           \
    (pgB)[1] = fmaf((float)(_aB1[1]*254 + _aB2[1]), _scB.y, _fB[1]);           \
    (pgB)[2] = fmaf((float)(_aB1[2]*254 + _aB2[2]), _scB.z, _fB[2]);           \
    (pgB)[3] = fmaf((float)(_aB1[3]*254 + _aB2[3]), _scB.w, _fB[3]);           \
  } while (0)

// Activation + state update + quant/store for row group I (literal 0..3).
#define ACT(I, pg) do {                                                        \
    const int _d = wid * 16 + (I) * 4 + lk;                                    \
    float4 _w17 = wih17_lds[_d];                                               \
    float _g0 = fmaf(_w17.x, zp_r, (pg)[0]);                                   \
    float _g1 = fmaf(_w17.y, zp_r, (pg)[1]);                                   \
    float _g2 = fmaf(_w17.z, zp_r, (pg)[2]);                                   \
    float _g3 = fmaf(_w17.w, zp_r, (pg)[3]);                                   \
    float _ig = sig2(_g0), _fg = sig2(_g1);                                    \
    float _gc = tanh2(_g2), _og = sig2(_g3);                                   \
    float _cc = fmaf(_fg, c_r[(I)], _ig * _gc);                                \
    c_r[(I)] = _cc;                                                            \
    float _hh = _og * tanhc(_cc);                                              \
    h_r[(I)] = _hh;                                                            \
    float _v = _hh * INV_SH;               /* |h|<1 -> no clamps needed */     \
    float _t1f = rintf(_v);                                                    \
    int   _t2i = (int)rintf((_v - _t1f) * 254.f);                              \
    int _e = (I) * 4 + lk;                                                     \
    int _addr = (wid * 16 + bcol) * 16 + _e;                                   \
    bf1n[_addr] = (char)(int)_t1f;                                             \
    bf2n[_addr] = (char)_t2i;                                                  \
    HBs[((wid >> 1) * 64 + ((wid & 1) * 2 + (_e >> 3)) * 16 + bcol) * 8 + (_e & 7)] \
        = (ushort)bf16rne(_hh);                                                \
  } while (0)

// One block = 16 batch, 16 waves, 1 CU. Two barriers per step:
//   combine : zp += delta(ts-1) (redundant), write out[ts-1]
//   phase A : pp=1 gate MFMAs(ts) with ACT(0/1) overlapped under their
//             latency, then merge + ACT(2/3); staging ds_write u(ts+1)
//   bar1
//   phase B : pp=0 gate MFMAs(ts+1) -> pgf01; FF(ts) on waves 0-3 (two
//             4-deep chains); staging global-load u(ts+2) into regs
//   bar2
__global__ __launch_bounds__(1024, 4) void lstm_kernel(
    const float* __restrict__ z, const float* __restrict__ x, const float* __restrict__ h0,
    const int4v* __restrict__ PA8, const uint4* __restrict__ WUg,
    const uint4* __restrict__ W1Pg, const float* __restrict__ SCL4g,
    const float* __restrict__ W17g,
    const float* __restrict__ b1g, const float* __restrict__ W2,
    const float* __restrict__ b2, float* __restrict__ out) {
  __shared__ __align__(16) char   BF1s[2][4096];  // h term-1 i8 frags (dbuf)
  __shared__ __align__(16) char   BF2s[2][4096];  // h term-2 i8 frags (dbuf)
  __shared__ __align__(16) ushort HBs[4096];      // h bf16 frags (FF)
  __shared__ __align__(16) uint4  UF[2][64];      // u bf16 frags (dbuf)
  __shared__ __align__(16) uint4  W1ls[2048];     // W1 bf16 A-frags, 32 KB
  __shared__ __align__(16) uint4  WUls[4096];     // Wih/bias bf16 A-frags, 64 KB
  __shared__ __align__(16) float4 scl_lds[256];   // folded per-row W scales
  __shared__ __align__(16) float4 wih17_lds[256]; // folded f32 Wih col 17
  __shared__ __align__(16) float  pslot[64];      // delta partials [16][4]
  __shared__ float b1_lds[64], w2_lds[64];

  const int t = threadIdx.x, l = t & 63, wid = t >> 6;
  const int bcol = l & 15, lk = l >> 4;
  const int b0 = blockIdx.x * GB;

  // ---- static register preloads: Whh int8 A-frags (64 regs, AGPR-resident) ----
  int4v wA[16];
  #pragma unroll
  for (int i = 0; i < 4; ++i)
    #pragma unroll
    for (int kt = 0; kt < 4; ++kt)
      wA[i * 4 + kt] = PA8[((wid * 4 + i) * 4 + kt) * 64 + l];
  const float b2v = b2[0];

  W1ls[t]        = W1Pg[t];
  W1ls[t + 1024] = W1Pg[t + 1024];
  #pragma unroll
  for (int q = 0; q < 4; ++q) WUls[q * 1024 + t] = WUg[q * 1024 + t];
  if (t < 256) scl_lds[t]   = ((const float4*)SCL4g)[t];
  if (t < 256) wih17_lds[t] = ((const float4*)W17g)[t];
  if (t < 64) { b1_lds[t] = b1g[t]; w2_lds[t] = W2[t]; }
  #pragma unroll
  for (int q = 0; q < 4; ++q) {   // h0 -> BF[0] (two-term, clamped: h0 unbounded)
    int idx = q * 1024 + t, d = idx >> 4, bb = idx & 15;
    float hv = h0[(b0 + bb) * H_ + d];
    int t1 = q8(hv * INV_SH);
    float rr = hv * INV_SH - (float)t1;
    int t2i = q8(rr * 254.f);
    int addr = ((d >> 6) * 64 + ((d >> 4) & 3) * 16 + bb) * 16 + (d & 15);
    BF1s[0][addr] = (char)t1;
    BF2s[0][addr] = (char)t2i;
  }

  float ld0 = 0.f, ld1 = 0.f;
  auto load_u = [&](int tn) {     // t in [768,1024): one dword each
    int st = t - 768;
    int bb = (st >> 2) & 15, lk2 = st >> 6, jj = st & 3;
    int k0 = lk2 * 8 + jj * 2, k1 = k0 + 1;
    const float* xb = &x[((b0 + bb) * T_ + tn) * 16];
    ld0 = (k0 == 0) ? 1.f
        : (k0 == 1) ? z[(b0 + bb) * T_ + tn]
        : (k0 <= 17) ? xb[k0 - 2] : 0.f;
    ld1 = (k1 == 1) ? z[(b0 + bb) * T_ + tn]
        : (k1 <= 17) ? xb[k1 - 2] : 0.f;
  };
  auto write_u = [&](int pu) {
    int st = t - 768;
    int bb = (st >> 2) & 15, lk2 = st >> 6, jj = st & 3;
    ((unsigned*)UF[pu])[(lk2 * 16 + bb) * 4 + jj] = bf16rne(ld0) | (bf16rne(ld1) << 16);
  };

  if (t >= 768) { load_u(0); write_u(0); load_u(1); }
  float c_r[4] = {0.f, 0.f, 0.f, 0.f}, h_r[4] = {0.f, 0.f, 0.f, 0.f};
  float zp_r = 0.f;
  float4v pgf0, pgf1;
  __syncthreads();                // h0 frags + UF(0) + LDS weights visible
  GATE_MFMA(0, 0, 0, pgf0, pgf1, ;);   // pgf01 for step 0

  int p = 0;
  for (int ts = 0; ts < T_; ++ts) {
    // ---- combine: zp(ts) = zp(ts-1) + delta(ts-1); write out[ts-1] ----
    if (ts) {
      float4 ps = ((const float4*)pslot)[bcol];
      float delta = fmaxf((ps.x + ps.y) + (ps.z + ps.w) + b2v, 0.f);
      zp_r += delta;
      if (wid == 15 && l < 16) out[(b0 + l) * T_ + ts - 1] = zp_r;
    }
    char* bf1n = BF1s[p ^ 1];
    char* bf2n = BF2s[p ^ 1];
    if (t >= 768 && ts + 1 < T_) write_u(p ^ 1);   // u(ts+1) from prefetch regs

    // ---- phase A: pp=1 MFMAs(ts) with ACT(0/1) under their latency ----
    {
      float4v pg2, pg3;
      GATE_MFMA(p, p, 1, pg2, pg3,
        ACT(0, pgf0);
        ACT(1, pgf1);
      );
      ACT(2, pg2);
      ACT(3, pg3);
    }
    __syncthreads();   // (1) h(ts) frags + u(ts+1) visible

    // ---- phase B: pp=0 MFMAs(ts+1) || FF(ts) || u(ts+2) prefetch ----
    if (t >= 768 && ts + 2 < T_) load_u(ts + 2);   // latency hides under MFMAs
    if (ts + 1 < T_) { GATE_MFMA(p ^ 1, p ^ 1, 0, pgf0, pgf1, ;); }
    if (wid < 4) {
      float4v fa0 = (float4v){0.f,0.f,0.f,0.f}, fa1 = (float4v){0.f,0.f,0.f,0.f};
      const short* w1s = (const short*)W1ls;
      #pragma unroll
      for (int kt = 0; kt < 4; ++kt) {   // two independent 4-deep chains
        short8 bfA = *(const short8*)&HBs[((2*kt)   * 64 + l) * 8];
        short8 wfA = *(const short8*)&w1s[((wid * 8 + 2*kt)   * 64 + l) * 8];
        fa0 = __builtin_amdgcn_mfma_f32_16x16x32_bf16(wfA, bfA, fa0, 0, 0, 0);
        short8 bfB = *(const short8*)&HBs[((2*kt+1) * 64 + l) * 8];
        short8 wfB = *(const short8*)&w1s[((wid * 8 + 2*kt+1) * 64 + l) * 8];
        fa1 = __builtin_amdgcn_mfma_f32_16x16x32_bf16(wfB, bfB, fa1, 0, 0, 0);
      }
      float s = 0.f;
      #pragma unroll
      for (int r = 0; r < 4; ++r) {
        int j = wid * 16 + lk * 4 + r;
        s = fmaf(w2_lds[j], fmaxf(fa0[r] + fa1[r] + b1_lds[j], 0.f), s);
      }
      s += __shfl_xor(s, 16);          // reduce over lk (same bcol)
      s += __shfl_xor(s, 32);
      if (l < 16) pslot[l * 4 + wid] = s;   // transposed: [batch][wave]
    }
    __syncthreads();   // (2) pslot ready
    p ^= 1;
  }

  // ---- epilogue: final combine + out[T-1], then h/c outputs ----
  {
    float4 ps = ((const float4*)pslot)[bcol];
    float delta = fmaxf((ps.x + ps.y) + (ps.z + ps.w) + b2v, 0.f);
    zp_r += delta;
    if (wid == 15 && l < 16) out[(b0 + l) * T_ + T_ - 1] = zp_r;
  }
  #pragma unroll
  for (int i = 0; i < 4; ++i) {
    int d = wid * 16 + i * 4 + lk;
    out[B_ * T_ + (b0 + bcol) * H_ + d]            = h_r[i];
    out[B_ * T_ + B_ * H_ + (b0 + bcol) * H_ + d]  = c_r[i];
  }
}

extern "C" void kernel_launch(void* const* d_in, const int* in_sizes, int n_in,
                              void* d_out, int out_size, void* d_ws, size_t ws_size,
                              hipStream_t stream) {
  const float* z   = (const float*)d_in[0];
  const float* x   = (const float*)d_in[1];
  const float* h0  = (const float*)d_in[2];
  const float* Wih = (const float*)d_in[3];
  const float* Whh = (const float*)d_in[4];
  const float* b   = (const float*)d_in[5];
  const float* W1  = (const float*)d_in[6];
  const float* b1  = (const float*)d_in[7];
  const float* W2  = (const float*)d_in[8];
  const float* b2  = (const float*)d_in[9];
  float* out = (float*)d_out;

  char* ws = (char*)d_ws;
  uint4* PA8   = (uint4*)(ws);             // 16384*16 = 262144 B
  uint4* W1Pg  = (uint4*)(ws + 262144);    //  2048*16 =  32768 B
  uint4* WU    = (uint4*)(ws + 294912);    //  4096*16 =  65536 B
  float* SCL4  = (float*)(ws + 360448);    //  1024*4  =   4096 B
  float* Mraw  = (float*)(ws + 364544);    //  1024*4  =   4096 B
  float* WIH17 = (float*)(ws + 368640);    //  1024*4  =   4096 B

  pack_scales<<<1024, 256, 0, stream>>>(Whh, Wih, Mraw, SCL4, WIH17);
  int total = 16384 + 2048 + 4096;
  pack_frags<<<(total + 255) / 256, 256, 0, stream>>>(Wih, Whh, b, W1, Mraw,
                                                      PA8, W1Pg, WU);
  lstm_kernel<<<NBLK, 1024, 0, stream>>>(z, x, h0, (const int4v*)PA8, (const uint4*)WU,
                                         W1Pg, SCL4, WIH17, b1, W2, b2, out);
}

// Round 4
// 779.490 us; speedup vs baseline: 1.7055x; 1.0568x over previous
//
#include <hip/hip_runtime.h>
#include <hip/hip_bf16.h>

typedef __attribute__((ext_vector_type(8))) short  short8;
typedef __attribute__((ext_vector_type(4))) int    int4v;
typedef __attribute__((ext_vector_type(4))) float  float4v;

#define B_   256
#define T_   200
#define H_   256
#define GB   16
#define NBLK 16
#define FWD_ 64
#define S_H    5.0f
#define INV_SH 25.4f            // 127/S_H
#define NL2E  (-1.44269504f)    // -log2(e)   (sigmoid gates, pre-folded)
#define NL2E2 (-2.88539008f)    // -2*log2(e) (tanh gate, pre-folded)

__device__ __forceinline__ float sig2(float gp) {   // gp = -log2e * g
  return __builtin_amdgcn_rcpf(1.f + __builtin_amdgcn_exp2f(gp));
}
__device__ __forceinline__ float tanh2(float gp) {  // gp = -2log2e * g
  return fmaf(__builtin_amdgcn_rcpf(1.f + __builtin_amdgcn_exp2f(gp)), 2.f, -1.f);
}
__device__ __forceinline__ float tanhc(float c) {   // raw units
  return fmaf(__builtin_amdgcn_rcpf(1.f + __builtin_amdgcn_exp2f(c * NL2E2)), 2.f, -1.f);
}
__device__ __forceinline__ unsigned bf16rne(float x) {
  unsigned u = __float_as_uint(x);
  return (u + 0x7FFFu + ((u >> 16) & 1u)) >> 16;
}
__device__ __forceinline__ int q8(float v) {
  float r = rintf(v);
  r = fminf(fmaxf(r, -127.f), 127.f);
  return (int)r;
}

// lgkmcnt-only barrier: LDS producer/consumer ordering WITHOUT draining vmcnt
// (prefetch loads + out[] stores stay in flight across the barrier — T4).
#define BAR() asm volatile("s_waitcnt lgkmcnt(0)\n\ts_barrier" ::: "memory")

// ---------- pack stage 1: per-ROW max-abs of Whh (+ folded scale, Wih col17) ----------
__global__ void pack_scales(const float* __restrict__ Whh, const float* __restrict__ Wih,
                            float* __restrict__ Mraw, float* __restrict__ SCL4,
                            float* __restrict__ WIH17) {
  __shared__ float red[4];
  int orow = blockIdx.x, tt = threadIdx.x;
  float m = fabsf(Whh[orow * 256 + tt]);
  #pragma unroll
  for (int off = 32; off; off >>= 1) m = fmaxf(m, __shfl_xor(m, off));
  if ((tt & 63) == 0) red[tt >> 6] = m;
  __syncthreads();
  if (tt == 0) {
    m = fmaxf(fmaxf(red[0], red[1]), fmaxf(red[2], red[3]));
    m = fmaxf(m, 1e-20f);
    Mraw[orow] = m;
    float fac = ((orow >> 8) == 2) ? NL2E2 : NL2E;  // gate 2 = cell tanh
    // SCL4 as float4[d]: component g = scale of row (d + g*256).
    // /254 for exact two-term merge qc=254*a1+a2; *fac folds exp->exp2 + sign.
    SCL4[(orow & 255) * 4 + (orow >> 8)] = m * (S_H / 16129.f / 254.f) * fac;
    WIH17[(orow & 255) * 4 + (orow >> 8)] = Wih[orow * 18 + 17] * fac;
  }
}

// ---------- pack stage 2: fragments ----------
// Gate-row permutation: A-row R = mt*16 + rho maps to unit d, gate g via
//   d = (mt>>2)*16 + (rho>>2)*4 + (mt&3),  g = rho&3
// so a lane's 4 accumulator groups (i=0..3) cover CONSECUTIVE units
// d = wid*16 + lk*4 + i  ->  packed b32/b64 LDS writes in ACT (conflict-free).
__global__ void pack_frags(const float* __restrict__ Wih, const float* __restrict__ Whh,
                           const float* __restrict__ b,   const float* __restrict__ W1,
                           const float* __restrict__ Mraw,
                           uint4* __restrict__ PA8, uint4* __restrict__ W1Pg,
                           uint4* __restrict__ WU) {
  int tid = blockIdx.x * blockDim.x + threadIdx.x;
  if (tid < 16384) {
    int mt = tid >> 8, rem = tid & 255, kt = rem >> 6, l = rem & 63;
    int rho = l & 15;
    int d = (mt >> 2) * 16 + (rho >> 2) * 4 + (mt & 3), g = rho & 3, orow = d + g * 256;
    int kb = kt * 64 + (l >> 4) * 16;
    float qs = 127.f / Mraw[orow];
    unsigned w[4];
    #pragma unroll
    for (int jj = 0; jj < 4; ++jj) {
      unsigned acc = 0;
      #pragma unroll
      for (int s = 0; s < 4; ++s) {
        int q = q8(Whh[orow * 256 + kb + jj * 4 + s] * qs);
        acc |= ((unsigned)(q & 255)) << (8 * s);
      }
      w[jj] = acc;
    }
    PA8[tid] = make_uint4(w[0], w[1], w[2], w[3]);
    return;
  }
  int t2 = tid - 16384;
  if (t2 >= 0 && t2 < 2048) {
    int l = t2 & 63, kt = (t2 >> 6) & 7, mt = t2 >> 9;
    int row = mt * 16 + (l & 15), kb = kt * 32 + (l >> 4) * 8;
    unsigned w[4];
    #pragma unroll
    for (int jj = 0; jj < 4; ++jj) {
      unsigned lo = bf16rne(W1[row * 256 + kb + jj * 2 + 0]);
      unsigned hi = bf16rne(W1[row * 256 + kb + jj * 2 + 1]);
      w[jj] = lo | (hi << 16);
    }
    W1Pg[t2] = make_uint4(w[0], w[1], w[2], w[3]);
    return;
  }
  int t3 = t2 - 2048;
  if (t3 >= 0 && t3 < 4096) {
    int mt = t3 >> 6, l = t3 & 63;
    int rho = l & 15;
    int d = (mt >> 2) * 16 + (rho >> 2) * 4 + (mt & 3), g = rho & 3, orow = d + g * 256;
    float fac = (g == 2) ? NL2E2 : NL2E;
    unsigned w[4];
    #pragma unroll
    for (int jj = 0; jj < 4; ++jj) {
      unsigned lohi[2];
      #pragma unroll
      for (int s = 0; s < 2; ++s) {
        int k = (l >> 4) * 8 + jj * 2 + s;
        float v = (k == 0) ? b[orow]
                : (k <= 18) ? Wih[orow * 18 + (k - 1)]
                : (k == 19) ? Wih[orow * 18 + 17] : 0.f;
        lohi[s] = bf16rne(v * fac);
      }
      w[jj] = lohi[0] | (lohi[1] << 16);
    }
    WU[t3] = make_uint4(w[0], w[1], w[2], w[3]);
  }
}

// Issues PP's 16 i8 + 2 bf16 MFMAs, runs ACTS (independent VALU) under their
// latency, then merges into pgA/pgB. PP literal at call site (wA index).
#define GATE_MFMA(PB, PU, PP, pgA, pgB, ...) do {                              \
    const short8* _wuls = (const short8*)WUls;                                 \
    short8 _uf  = ((const short8*)UF[(PU)])[l];                                \
    short8 _wuA = _wuls[(wid * 4 + (PP) * 2 + 0) * 64 + l];                    \
    short8 _wuB = _wuls[(wid * 4 + (PP) * 2 + 1) * 64 + l];                    \
    int4v _aA1 = {0,0,0,0}, _aA2 = {0,0,0,0};                                  \
    int4v _aB1 = {0,0,0,0}, _aB2 = {0,0,0,0};                                  \
    _Pragma("unroll")                                                          \
    for (int _kt = 0; _kt < 4; ++_kt) {                                        \
      int4v _bq1 = *(const int4v*)&BF1s[(PB)][(_kt * 64 + l) * 16];            \
      int4v _bq2 = *(const int4v*)&BF2s[(PB)][(_kt * 64 + l) * 16];            \
      _aA1 = __builtin_amdgcn_mfma_i32_16x16x64_i8(wA[((PP)*2+0)*4+_kt], _bq1, _aA1, 0,0,0); \
      _aA2 = __builtin_amdgcn_mfma_i32_16x16x64_i8(wA[((PP)*2+0)*4+_kt], _bq2, _aA2, 0,0,0); \
      _aB1 = __builtin_amdgcn_mfma_i32_16x16x64_i8(wA[((PP)*2+1)*4+_kt], _bq1, _aB1, 0,0,0); \
      _aB2 = __builtin_amdgcn_mfma_i32_16x16x64_i8(wA[((PP)*2+1)*4+_kt], _bq2, _aB2, 0,0,0); \
    }                                                                          \
    float4v _fA = __builtin_amdgcn_mfma_f32_16x16x32_bf16(_wuA, _uf, (float4v){0.f,0.f,0.f,0.f}, 0,0,0); \
    float4v _fB = __builtin_amdgcn_mfma_f32_16x16x32_bf16(_wuB, _uf, (float4v){0.f,0.f,0.f,0.f}, 0,0,0); \
    __VA_ARGS__                                                                \
    float4 _scA = scl_lds[wid * 16 + lk * 4 + ((PP) * 2 + 0)];                 \
    float4 _scB = scl_lds[wid * 16 + lk * 4 + ((PP) * 2 + 1)];                 \
    (pgA)[0] = fmaf((float)(_aA1[0]*254 + _aA2[0]), _scA.x, _fA[0]);           \
    (pgA)[1] = fmaf((float)(_aA1[1]*254 + _aA2[1]), _scA.y, _fA[1]);           \
    (pgA)[2] = fmaf((float)(_aA1[2]*254 + _aA2[2]), _scA.z, _fA[2]);           \
    (pgA)[3] = fmaf((float)(_aA1[3]*254 + _aA2[3]), _scA.w, _fA[3]);           \
    (pgB)[0] = fmaf((float)(_aB1[0]*254 + _aB2[0]), _scB.x, _fB[0]);           \
    (pgB)[1] = fmaf((float)(_aB1[1]*254 + _aB2[1]), _scB.y, _fB[1]);           \
    (pgB)[2] = fmaf((float)(_aB1[2]*254 + _aB2[2]), _scB.z, _fB[2]);           \
    (pgB)[3] = fmaf((float)(_aB1[3]*254 + _aB2[3]), _scB.w, _fB[3]);           \
  } while (0)

// Activation + state update + quant for unit d = wid*16 + lk*4 + I (I literal).
// Quant bytes accumulate into bf1pk/bf2pk/hb0/hb1; stores happen once after ACT(3).
#define ACT(I, pg) do {                                                        \
    const int _d = wid * 16 + lk * 4 + (I);                                    \
    float4 _w17 = wih17_lds[_d];                                               \
    float _g0 = fmaf(_w17.x, zp_r, (pg)[0]);                                   \
    float _g1 = fmaf(_w17.y, zp_r, (pg)[1]);                                   \
    float _g2 = fmaf(_w17.z, zp_r, (pg)[2]);                                   \
    float _g3 = fmaf(_w17.w, zp_r, (pg)[3]);                                   \
    float _ig = sig2(_g0), _fg = sig2(_g1);                                    \
    float _gc = tanh2(_g2), _og = sig2(_g3);                                   \
    float _cc = fmaf(_fg, c_r[(I)], _ig * _gc);                                \
    c_r[(I)] = _cc;                                                            \
    float _hh = _og * tanhc(_cc);                                              \
    h_r[(I)] = _hh;                                                            \
    float _v = _hh * INV_SH;               /* |h|<1 -> no clamps needed */     \
    float _t1f = rintf(_v);                                                    \
    int   _t2i = (int)rintf((_v - _t1f) * 254.f);                              \
    unsigned _b1 = ((unsigned)((int)_t1f & 255)) << (8 * (I));                 \
    unsigned _b2 = ((unsigned)(_t2i & 255)) << (8 * (I));                      \
    if ((I) == 0) { bf1pk = _b1; bf2pk = _b2; }                                \
    else          { bf1pk |= _b1; bf2pk |= _b2; }                              \
    unsigned _hb = bf16rne(_hh);                                               \
    if ((I) == 0) hb0 = _hb; else if ((I) == 1) hb0 |= _hb << 16;              \
    else if ((I) == 2) hb1 = _hb; else hb1 |= _hb << 16;                       \
  } while (0)

// One block = 16 batch, 16 waves, 1 CU. Two lgkm-only barriers per step:
//   combine : zp += delta(ts-1) (redundant per-thread), out[ts-1] on wave 4
//   phase A : pp=1 gate MFMAs(ts) with ACT(0/1) under their latency, then
//             merge + ACT(2/3); packed b32/b32/b64 h-frag stores; staging
//             waves ds_write u(ts+1)
//   BAR1 (lgkmcnt only)
//   phase B : pp=0 gate MFMAs(ts+1) -> pgf01; FF(ts) on waves 0-3 (setprio-
//             boosted: they are the barrier laggard); staging global-load
//             u(ts+2) stays in flight across BAR2
//   BAR2 (lgkmcnt only)
__global__ __launch_bounds__(1024, 4) void lstm_kernel(
    const float* __restrict__ z, const float* __restrict__ x, const float* __restrict__ h0,
    const int4v* __restrict__ PA8, const uint4* __restrict__ WUg,
    const uint4* __restrict__ W1Pg, const float* __restrict__ SCL4g,
    const float* __restrict__ W17g,
    const float* __restrict__ b1g, const float* __restrict__ W2,
    const float* __restrict__ b2, float* __restrict__ out) {
  __shared__ __align__(16) char   BF1s[2][4096];  // h term-1 i8 frags (dbuf)
  __shared__ __align__(16) char   BF2s[2][4096];  // h term-2 i8 frags (dbuf)
  __shared__ __align__(16) ushort HBs[4096];      // h bf16 frags (FF)
  __shared__ __align__(16) uint4  UF[2][64];      // u bf16 frags (dbuf)
  __shared__ __align__(16) uint4  W1ls[2048];     // W1 bf16 A-frags, 32 KB
  __shared__ __align__(16) uint4  WUls[4096];     // Wih/bias bf16 A-frags, 64 KB
  __shared__ __align__(16) float4 scl_lds[256];   // folded per-row W scales
  __shared__ __align__(16) float4 wih17_lds[256]; // folded f32 Wih col 17
  __shared__ __align__(16) float  pslot[64];      // delta partials [16][4]
  __shared__ float b1_lds[64], w2_lds[64];

  const int t = threadIdx.x, l = t & 63, wid = t >> 6;
  const int bcol = l & 15, lk = l >> 4;
  const int b0 = blockIdx.x * GB;

  // ---- static register preloads: Whh int8 A-frags (64 regs, AGPR-resident) ----
  int4v wA[16];
  #pragma unroll
  for (int i = 0; i < 4; ++i)
    #pragma unroll
    for (int kt = 0; kt < 4; ++kt)
      wA[i * 4 + kt] = PA8[((wid * 4 + i) * 4 + kt) * 64 + l];
  const float b2v = b2[0];

  W1ls[t]        = W1Pg[t];
  W1ls[t + 1024] = W1Pg[t + 1024];
  #pragma unroll
  for (int q = 0; q < 4; ++q) WUls[q * 1024 + t] = WUg[q * 1024 + t];
  if (t < 256) scl_lds[t]   = ((const float4*)SCL4g)[t];
  if (t < 256) wih17_lds[t] = ((const float4*)W17g)[t];
  if (t < 64) { b1_lds[t] = b1g[t]; w2_lds[t] = W2[t]; }
  #pragma unroll
  for (int q = 0; q < 4; ++q) {   // h0 -> BF[0] (two-term, clamped: h0 unbounded)
    int idx = q * 1024 + t, d = idx >> 4, bb = idx & 15;
    float hv = h0[(b0 + bb) * H_ + d];
    int t1 = q8(hv * INV_SH);
    float rr = hv * INV_SH - (float)t1;
    int t2i = q8(rr * 254.f);
    int addr = ((d >> 6) * 64 + ((d >> 4) & 3) * 16 + bb) * 16 + (d & 15);
    BF1s[0][addr] = (char)t1;
    BF2s[0][addr] = (char)t2i;
  }

  float ld0 = 0.f, ld1 = 0.f;
  auto load_u = [&](int tn) {     // t in [768,1024): one dword each
    int st = t - 768;
    int bb = (st >> 2) & 15, lk2 = st >> 6, jj = st & 3;
    int k0 = lk2 * 8 + jj * 2, k1 = k0 + 1;
    const float* xb = &x[((b0 + bb) * T_ + tn) * 16];
    ld0 = (k0 == 0) ? 1.f
        : (k0 == 1) ? z[(b0 + bb) * T_ + tn]
        : (k0 <= 17) ? xb[k0 - 2] : 0.f;
    ld1 = (k1 == 1) ? z[(b0 + bb) * T_ + tn]
        : (k1 <= 17) ? xb[k1 - 2] : 0.f;
  };
  auto write_u = [&](int pu) {
    int st = t - 768;
    int bb = (st >> 2) & 15, lk2 = st >> 6, jj = st & 3;
    ((unsigned*)UF[pu])[(lk2 * 16 + bb) * 4 + jj] = bf16rne(ld0) | (bf16rne(ld1) << 16);
  };

  if (t >= 768) { load_u(0); write_u(0); load_u(1); }
  float c_r[4] = {0.f, 0.f, 0.f, 0.f}, h_r[4] = {0.f, 0.f, 0.f, 0.f};
  float zp_r = 0.f;
  float4v pgf0, pgf1;
  __syncthreads();                // prologue full sync (h0 frags + LDS weights)
  GATE_MFMA(0, 0, 0, pgf0, pgf1, ;);   // pgf01 for step 0

  int p = 0;
  for (int ts = 0; ts < T_; ++ts) {
    // ---- combine: zp(ts) = zp(ts-1) + delta(ts-1); write out[ts-1] ----
    if (ts) {
      float4 ps = ((const float4*)pslot)[bcol];
      float delta = fmaxf((ps.x + ps.y) + (ps.z + ps.w) + b2v, 0.f);
      zp_r += delta;
      if (wid == 4 && l < 16) out[(b0 + l) * T_ + ts - 1] = zp_r;
    }
    char* bf1n = BF1s[p ^ 1];
    char* bf2n = BF2s[p ^ 1];
    if (t >= 768 && ts + 1 < T_) write_u(p ^ 1);   // u(ts+1) from prefetch regs

    // ---- phase A: pp=1 MFMAs(ts) with ACT(0/1) under their latency ----
    {
      unsigned bf1pk, bf2pk, hb0, hb1;
      float4v pg2, pg3;
      GATE_MFMA(p, p, 1, pg2, pg3,
        ACT(0, pgf0);
        ACT(1, pgf1);
      );
      ACT(2, pg2);
      ACT(3, pg3);
      // packed h-frag stores: one b32 per i8 buffer, one b64 for bf16
      *(unsigned*)&bf1n[(wid * 16 + bcol) * 16 + lk * 4] = bf1pk;
      *(unsigned*)&bf2n[(wid * 16 + bcol) * 16 + lk * 4] = bf2pk;
      int hbase = ((wid >> 1) * 64 + ((wid & 1) * 2 + (lk >> 1)) * 16 + bcol) * 8
                + (lk & 1) * 4;
      uint2 hv; hv.x = hb0; hv.y = hb1;
      *(uint2*)&HBs[hbase] = hv;
    }
    BAR();             // (1) h(ts) frags + u(ts+1) visible; vmem stays in flight

    // ---- phase B: pp=0 MFMAs(ts+1) || FF(ts) || u(ts+2) prefetch ----
    if (t >= 768 && ts + 2 < T_) load_u(ts + 2);   // in flight across BAR2
    if (ts + 1 < T_) { GATE_MFMA(p ^ 1, p ^ 1, 0, pgf0, pgf1, ;); }
    if (wid < 4) {
      __builtin_amdgcn_s_setprio(1);               // FF waves are the laggard
      float4v fa0 = (float4v){0.f,0.f,0.f,0.f}, fa1 = (float4v){0.f,0.f,0.f,0.f};
      const short* w1s = (const short*)W1ls;
      #pragma unroll
      for (int kt = 0; kt < 4; ++kt) {   // two independent 4-deep chains
        short8 bfA = *(const short8*)&HBs[((2*kt)   * 64 + l) * 8];
        short8 wfA = *(const short8*)&w1s[((wid * 8 + 2*kt)   * 64 + l) * 8];
        fa0 = __builtin_amdgcn_mfma_f32_16x16x32_bf16(wfA, bfA, fa0, 0, 0, 0);
        short8 bfB = *(const short8*)&HBs[((2*kt+1) * 64 + l) * 8];
        short8 wfB = *(const short8*)&w1s[((wid * 8 + 2*kt+1) * 64 + l) * 8];
        fa1 = __builtin_amdgcn_mfma_f32_16x16x32_bf16(wfB, bfB, fa1, 0, 0, 0);
      }
      float s = 0.f;
      #pragma unroll
      for (int r = 0; r < 4; ++r) {
        int j = wid * 16 + lk * 4 + r;
        s = fmaf(w2_lds[j], fmaxf(fa0[r] + fa1[r] + b1_lds[j], 0.f), s);
      }
      s += __shfl_xor(s, 16);          // reduce over lk (same bcol)
      s += __shfl_xor(s, 32);
      if (l < 16) pslot[l * 4 + wid] = s;   // transposed: [batch][wave]
      __builtin_amdgcn_s_setprio(0);
    }
    BAR();             // (2) pslot ready; prefetch loads stay in flight
    p ^= 1;
  }

  // ---- epilogue: final combine + out[T-1], then h/c outputs ----
  {
    float4 ps = ((const float4*)pslot)[bcol];
    float delta = fmaxf((ps.x + ps.y) + (ps.z + ps.w) + b2v, 0.f);
    zp_r += delta;
    if (wid == 4 && l < 16) out[(b0 + l) * T_ + T_ - 1] = zp_r;
  }
  #pragma unroll
  for (int i = 0; i < 4; ++i) {
    int d = wid * 16 + lk * 4 + i;
    out[B_ * T_ + (b0 + bcol) * H_ + d]            = h_r[i];
    out[B_ * T_ + B_ * H_ + (b0 + bcol) * H_ + d]  = c_r[i];
  }
}

extern "C" void kernel_launch(void* const* d_in, const int* in_sizes, int n_in,
                              void* d_out, int out_size, void* d_ws, size_t ws_size,
                              hipStream_t stream) {
  const float* z   = (const float*)d_in[0];
  const float* x   = (const float*)d_in[1];
  const float* h0  = (const float*)d_in[2];
  const float* Wih = (const float*)d_in[3];
  const float* Whh = (const float*)d_in[4];
  const float* b   = (const float*)d_in[5];
  const float* W1  = (const float*)d_in[6];
  const float* b1  = (const float*)d_in[7];
  const float* W2  = (const float*)d_in[8];
  const float* b2  = (const float*)d_in[9];
  float* out = (float*)d_out;

  char* ws = (char*)d_ws;
  uint4* PA8   = (uint4*)(ws);             // 16384*16 = 262144 B
  uint4* W1Pg  = (uint4*)(ws + 262144);    //  2048*16 =  32768 B
  uint4* WU    = (uint4*)(ws + 294912);    //  4096*16 =  65536 B
  float* SCL4  = (float*)(ws + 360448);    //  1024*4  =   4096 B
  float* Mraw  = (float*)(ws + 364544);    //  1024*4  =   4096 B
  float* WIH17 = (float*)(ws + 368640);    //  1024*4  =   4096 B

  pack_scales<<<1024, 256, 0, stream>>>(Whh, Wih, Mraw, SCL4, WIH17);
  int total = 16384 + 2048 + 4096;
  pack_frags<<<(total + 255) / 256, 256, 0, stream>>>(Wih, Whh, b, W1, Mraw,
                                                      PA8, W1Pg, WU);
  lstm_kernel<<<NBLK, 1024, 0, stream>>>(z, x, h0, (const int4v*)PA8, (const uint4*)WU,
                                         W1Pg, SCL4, WIH17, b1, W2, b2, out);
}

// Round 6
// 656.526 us; speedup vs baseline: 2.0250x; 1.1873x over previous
//
#include <hip/hip_runtime.h>
#include <hip/hip_bf16.h>

typedef __attribute__((ext_vector_type(8))) short  short8;
typedef __attribute__((ext_vector_type(4))) int    int4v;
typedef __attribute__((ext_vector_type(4))) float  float4v;

#define B_   256
#define T_   200
#define H_   256
#define GB   16
#define NBLK 16
#define FWD_ 64
#define S_H    5.0f
#define INV_SH 25.4f            // 127/S_H
#define NL2E  (-1.44269504f)    // -log2(e)   (sigmoid gates, pre-folded)
#define NL2E2 (-2.88539008f)    // -2*log2(e) (tanh gate, pre-folded)

__device__ __forceinline__ float sig2(float gp) {   // gp = -log2e * g
  return __builtin_amdgcn_rcpf(1.f + __builtin_amdgcn_exp2f(gp));
}
__device__ __forceinline__ float tanh2(float gp) {  // gp = -2log2e * g
  return fmaf(__builtin_amdgcn_rcpf(1.f + __builtin_amdgcn_exp2f(gp)), 2.f, -1.f);
}
__device__ __forceinline__ float tanhc(float c) {   // raw units
  return fmaf(__builtin_amdgcn_rcpf(1.f + __builtin_amdgcn_exp2f(c * NL2E2)), 2.f, -1.f);
}
// RNE f32->bf16. NOTE (R5 lesson): v_cvt_pk_bf16_f32 caused a systematic
// absmax blowup (0.117) — suspected truncation rounding. Keep explicit RNE.
__device__ __forceinline__ unsigned bf16rne(float x) {
  unsigned u = __float_as_uint(x);
  return (u + 0x7FFFu + ((u >> 16) & 1u)) >> 16;
}
__device__ __forceinline__ int q8(float v) {
  float r = rintf(v);
  r = fminf(fmaxf(r, -127.f), 127.f);
  return (int)r;
}

// lgkmcnt-only barrier: LDS producer/consumer ordering WITHOUT draining vmcnt
// (prefetch loads + out[] stores stay in flight across the barrier — T4).
#define BAR() asm volatile("s_waitcnt lgkmcnt(0)\n\ts_barrier" ::: "memory")

// ---------- pack stage 1: per-ROW max-abs of Whh (+ folded scale, Wih col17) ----------
__global__ void pack_scales(const float* __restrict__ Whh, const float* __restrict__ Wih,
                            float* __restrict__ Mraw, float* __restrict__ SCL4,
                            float* __restrict__ WIH17) {
  __shared__ float red[4];
  int orow = blockIdx.x, tt = threadIdx.x;
  float m = fabsf(Whh[orow * 256 + tt]);
  #pragma unroll
  for (int off = 32; off; off >>= 1) m = fmaxf(m, __shfl_xor(m, off));
  if ((tt & 63) == 0) red[tt >> 6] = m;
  __syncthreads();
  if (tt == 0) {
    m = fmaxf(fmaxf(red[0], red[1]), fmaxf(red[2], red[3]));
    m = fmaxf(m, 1e-20f);
    Mraw[orow] = m;
    float fac = ((orow >> 8) == 2) ? NL2E2 : NL2E;  // gate 2 = cell tanh
    // SCL4 as float4[d]: component g = scale of row (d + g*256).
    // /254 for exact two-term merge qc=mul24(a1,254)+a2; *fac folds exp->exp2.
    SCL4[(orow & 255) * 4 + (orow >> 8)] = m * (S_H / 16129.f / 254.f) * fac;
    WIH17[(orow & 255) * 4 + (orow >> 8)] = Wih[orow * 18 + 17] * fac;
  }
}

// ---------- pack stage 2: fragments ----------
// Gate-row permutation: A-row R = mt*16 + rho maps to unit d, gate g via
//   d = (mt>>2)*16 + (rho>>2)*4 + (mt&3),  g = rho&3
// so a lane's 4 accumulator groups (i=0..3) cover CONSECUTIVE units
// d = wid*16 + lk*4 + i  ->  packed b32/b64 LDS writes in ACT (conflict-free).
__global__ void pack_frags(const float* __restrict__ Wih, const float* __restrict__ Whh,
                           const float* __restrict__ b,   const float* __restrict__ W1,
                           const float* __restrict__ Mraw,
                           uint4* __restrict__ PA8, uint4* __restrict__ W1Pg,
                           uint4* __restrict__ WU) {
  int tid = blockIdx.x * blockDim.x + threadIdx.x;
  if (tid < 16384) {
    int mt = tid >> 8, rem = tid & 255, kt = rem >> 6, l = rem & 63;
    int rho = l & 15;
    int d = (mt >> 2) * 16 + (rho >> 2) * 4 + (mt & 3), g = rho & 3, orow = d + g * 256;
    int kb = kt * 64 + (l >> 4) * 16;
    float qs = 127.f / Mraw[orow];
    unsigned w[4];
    #pragma unroll
    for (int jj = 0; jj < 4; ++jj) {
      unsigned acc = 0;
      #pragma unroll
      for (int s = 0; s < 4; ++s) {
        int q = q8(Whh[orow * 256 + kb + jj * 4 + s] * qs);
        acc |= ((unsigned)(q & 255)) << (8 * s);
      }
      w[jj] = acc;
    }
    PA8[tid] = make_uint4(w[0], w[1], w[2], w[3]);
    return;
  }
  int t2 = tid - 16384;
  if (t2 >= 0 && t2 < 2048) {
    int l = t2 & 63, kt = (t2 >> 6) & 7, mt = t2 >> 9;
    int row = mt * 16 + (l & 15), kb = kt * 32 + (l >> 4) * 8;
    unsigned w[4];
    #pragma unroll
    for (int jj = 0; jj < 4; ++jj) {
      unsigned lo = bf16rne(W1[row * 256 + kb + jj * 2 + 0]);
      unsigned hi = bf16rne(W1[row * 256 + kb + jj * 2 + 1]);
      w[jj] = lo | (hi << 16);
    }
    W1Pg[t2] = make_uint4(w[0], w[1], w[2], w[3]);
    return;
  }
  int t3 = t2 - 2048;
  if (t3 >= 0 && t3 < 4096) {
    int mt = t3 >> 6, l = t3 & 63;
    int rho = l & 15;
    int d = (mt >> 2) * 16 + (rho >> 2) * 4 + (mt & 3), g = rho & 3, orow = d + g * 256;
    float fac = (g == 2) ? NL2E2 : NL2E;
    unsigned w[4];
    #pragma unroll
    for (int jj = 0; jj < 4; ++jj) {
      unsigned lohi[2];
      #pragma unroll
      for (int s = 0; s < 2; ++s) {
        int k = (l >> 4) * 8 + jj * 2 + s;
        float v = (k == 0) ? b[orow]
                : (k <= 18) ? Wih[orow * 18 + (k - 1)]
                : (k == 19) ? Wih[orow * 18 + 17] : 0.f;
        lohi[s] = bf16rne(v * fac);
      }
      w[jj] = lohi[0] | (lohi[1] << 16);
    }
    WU[t3] = make_uint4(w[0], w[1], w[2], w[3]);
  }
}

// Issues PP's 16 i8 + 2 bf16 MFMAs, runs the slot body (independent VALU /
// latency-bound LDS reads) under their latency, then merges into pgA/pgB.
// Merge: qc = __mul24(a1,254) + a2 — EXACT (|a1|<2^23, |qc|<2^31), bit-
// identical to the reference int path, but full-rate v_mul_i32_i24.
#define GATE_MFMA(PB, PU, PP, pgA, pgB, ...) do {                              \
    const short8* _wuls = (const short8*)WUls;                                 \
    short8 _uf  = ((const short8*)UF[(PU)])[l];                                \
    short8 _wuA = _wuls[(wid * 4 + (PP) * 2 + 0) * 64 + l];                    \
    short8 _wuB = _wuls[(wid * 4 + (PP) * 2 + 1) * 64 + l];                    \
    int4v _aA1 = {0,0,0,0}, _aA2 = {0,0,0,0};                                  \
    int4v _aB1 = {0,0,0,0}, _aB2 = {0,0,0,0};                                  \
    _Pragma("unroll")                                                          \
    for (int _kt = 0; _kt < 4; ++_kt) {                                        \
      int4v _bq1 = *(const int4v*)&BF1s[(PB)][(_kt * 64 + l) * 16];            \
      int4v _bq2 = *(const int4v*)&BF2s[(PB)][(_kt * 64 + l) * 16];            \
      _aA1 = __builtin_amdgcn_mfma_i32_16x16x64_i8(wA[((PP)*2+0)*4+_kt], _bq1, _aA1, 0,0,0); \
      _aA2 = __builtin_amdgcn_mfma_i32_16x16x64_i8(wA[((PP)*2+0)*4+_kt], _bq2, _aA2, 0,0,0); \
      _aB1 = __builtin_amdgcn_mfma_i32_16x16x64_i8(wA[((PP)*2+1)*4+_kt], _bq1, _aB1, 0,0,0); \
      _aB2 = __builtin_amdgcn_mfma_i32_16x16x64_i8(wA[((PP)*2+1)*4+_kt], _bq2, _aB2, 0,0,0); \
    }                                                                          \
    float4v _fA = __builtin_amdgcn_mfma_f32_16x16x32_bf16(_wuA, _uf, (float4v){0.f,0.f,0.f,0.f}, 0,0,0); \
    float4v _fB = __builtin_amdgcn_mfma_f32_16x16x32_bf16(_wuB, _uf, (float4v){0.f,0.f,0.f,0.f}, 0,0,0); \
    __VA_ARGS__                                                                \
    float4 _scA = scl_lds[wid * 16 + lk * 4 + ((PP) * 2 + 0)];                 \
    float4 _scB = scl_lds[wid * 16 + lk * 4 + ((PP) * 2 + 1)];                 \
    (pgA)[0] = fmaf((float)(__mul24(_aA1[0], 254) + _aA2[0]), _scA.x, _fA[0]); \
    (pgA)[1] = fmaf((float)(__mul24(_aA1[1], 254) + _aA2[1]), _scA.y, _fA[1]); \
    (pgA)[2] = fmaf((float)(__mul24(_aA1[2], 254) + _aA2[2]), _scA.z, _fA[2]); \
    (pgA)[3] = fmaf((float)(__mul24(_aA1[3], 254) + _aA2[3]), _scA.w, _fA[3]); \
    (pgB)[0] = fmaf((float)(__mul24(_aB1[0], 254) + _aB2[0]), _scB.x, _fB[0]); \
    (pgB)[1] = fmaf((float)(__mul24(_aB1[1], 254) + _aB2[1]), _scB.y, _fB[1]); \
    (pgB)[2] = fmaf((float)(__mul24(_aB1[2], 254) + _aB2[2]), _scB.z, _fB[2]); \
    (pgB)[3] = fmaf((float)(__mul24(_aB1[3], 254) + _aB2[3]), _scB.w, _fB[3]); \
  } while (0)

// Activation + state update + i8 quant for unit d = wid*16 + lk*4 + I (I literal).
// Quant bytes accumulate into bf1pk/bf2pk; h bf16 is packed from h_r after ACT(3).
#define ACT(I, pg) do {                                                        \
    const int _d = wid * 16 + lk * 4 + (I);                                    \
    float4 _w17 = wih17_lds[_d];                                               \
    float _g0 = fmaf(_w17.x, zp_r, (pg)[0]);                                   \
    float _g1 = fmaf(_w17.y, zp_r, (pg)[1]);                                   \
    float _g2 = fmaf(_w17.z, zp_r, (pg)[2]);                                   \
    float _g3 = fmaf(_w17.w, zp_r, (pg)[3]);                                   \
    float _ig = sig2(_g0), _fg = sig2(_g1);                                    \
    float _gc = tanh2(_g2), _og = sig2(_g3);                                   \
    float _cc = fmaf(_fg, c_r[(I)], _ig * _gc);                                \
    c_r[(I)] = _cc;                                                            \
    float _hh = _og * tanhc(_cc);                                              \
    h_r[(I)] = _hh;                                                            \
    float _v = _hh * INV_SH;               /* |h|<1 -> no clamps needed */     \
    float _t1f = rintf(_v);                                                    \
    int   _t2i = (int)rintf((_v - _t1f) * 254.f);                              \
    unsigned _b1 = ((unsigned)((int)_t1f & 255)) << (8 * (I));                 \
    unsigned _b2 = ((unsigned)(_t2i & 255)) << (8 * (I));                      \
    if ((I) == 0) { bf1pk = _b1; bf2pk = _b2; }                                \
    else          { bf1pk |= _b1; bf2pk |= _b2; }                              \
  } while (0)

// One block = 16 batch, 16 waves, 1 CU. Two lgkm-only barriers per step:
//   phase A : pp=1 gate MFMAs(ts); in their latency shadow: combine (pslot
//             ds_read + zp update + out[ts-1]) then ACT(0/1); merge; ACT(2/3);
//             packed b32/b32/b64 h-frag stores; staging waves ds_write u(ts+1)
//   BAR1 (lgkmcnt only)
//   phase B : pp=0 gate MFMAs(ts+1) -> pgf01; FF(ts) on waves 0-3 (setprio-
//             boosted: they are the barrier laggard); staging global-load
//             u(ts+2) stays in flight across BAR2
//   BAR2 (lgkmcnt only)
__global__ __launch_bounds__(1024, 4) void lstm_kernel(
    const float* __restrict__ z, const float* __restrict__ x, const float* __restrict__ h0,
    const int4v* __restrict__ PA8, const uint4* __restrict__ WUg,
    const uint4* __restrict__ W1Pg, const float* __restrict__ SCL4g,
    const float* __restrict__ W17g,
    const float* __restrict__ b1g, const float* __restrict__ W2,
    const float* __restrict__ b2, float* __restrict__ out) {
  __shared__ __align__(16) char   BF1s[2][4096];  // h term-1 i8 frags (dbuf)
  __shared__ __align__(16) char   BF2s[2][4096];  // h term-2 i8 frags (dbuf)
  __shared__ __align__(16) ushort HBs[4096];      // h bf16 frags (FF)
  __shared__ __align__(16) uint4  UF[2][64];      // u bf16 frags (dbuf)
  __shared__ __align__(16) uint4  W1ls[2048];     // W1 bf16 A-frags, 32 KB
  __shared__ __align__(16) uint4  WUls[4096];     // Wih/bias bf16 A-frags, 64 KB
  __shared__ __align__(16) float4 scl_lds[256];   // folded per-row W scales
  __shared__ __align__(16) float4 wih17_lds[256]; // folded f32 Wih col 17
  __shared__ __align__(16) float  pslot[64];      // delta partials [16][4]
  __shared__ float b1_lds[64], w2_lds[64];

  const int t = threadIdx.x, l = t & 63, wid = t >> 6;
  const int bcol = l & 15, lk = l >> 4;
  const int b0 = blockIdx.x * GB;

  // ---- static register preloads: Whh int8 A-frags (64 regs, AGPR-resident) ----
  int4v wA[16];
  #pragma unroll
  for (int i = 0; i < 4; ++i)
    #pragma unroll
    for (int kt = 0; kt < 4; ++kt)
      wA[i * 4 + kt] = PA8[((wid * 4 + i) * 4 + kt) * 64 + l];
  const float b2v = b2[0];

  W1ls[t]        = W1Pg[t];
  W1ls[t + 1024] = W1Pg[t + 1024];
  #pragma unroll
  for (int q = 0; q < 4; ++q) WUls[q * 1024 + t] = WUg[q * 1024 + t];
  if (t < 256) scl_lds[t]   = ((const float4*)SCL4g)[t];
  if (t < 256) wih17_lds[t] = ((const float4*)W17g)[t];
  if (t < 64) { b1_lds[t] = b1g[t]; w2_lds[t] = W2[t]; }
  #pragma unroll
  for (int q = 0; q < 4; ++q) {   // h0 -> BF[0] (two-term, clamped: h0 unbounded)
    int idx = q * 1024 + t, d = idx >> 4, bb = idx & 15;
    float hv = h0[(b0 + bb) * H_ + d];
    int t1 = q8(hv * INV_SH);
    float rr = hv * INV_SH - (float)t1;
    int t2i = q8(rr * 254.f);
    int addr = ((d >> 6) * 64 + ((d >> 4) & 3) * 16 + bb) * 16 + (d & 15);
    BF1s[0][addr] = (char)t1;
    BF2s[0][addr] = (char)t2i;
  }

  float ld0 = 0.f, ld1 = 0.f;
  auto load_u = [&](int tn) {     // t in [768,1024): one dword each
    int st = t - 768;
    int bb = (st >> 2) & 15, lk2 = st >> 6, jj = st & 3;
    int k0 = lk2 * 8 + jj * 2, k1 = k0 + 1;
    const float* xb = &x[((b0 + bb) * T_ + tn) * 16];
    ld0 = (k0 == 0) ? 1.f
        : (k0 == 1) ? z[(b0 + bb) * T_ + tn]
        : (k0 <= 17) ? xb[k0 - 2] : 0.f;
    ld1 = (k1 == 1) ? z[(b0 + bb) * T_ + tn]
        : (k1 <= 17) ? xb[k1 - 2] : 0.f;
  };
  auto write_u = [&](int pu) {
    int st = t - 768;
    int bb = (st >> 2) & 15, lk2 = st >> 6, jj = st & 3;
    ((unsigned*)UF[pu])[(lk2 * 16 + bb) * 4 + jj] = bf16rne(ld0) | (bf16rne(ld1) << 16);
  };

  if (t >= 768) { load_u(0); write_u(0); load_u(1); }
  float c_r[4] = {0.f, 0.f, 0.f, 0.f}, h_r[4] = {0.f, 0.f, 0.f, 0.f};
  float zp_r = 0.f;
  float4v pgf0, pgf1;
  __syncthreads();                // prologue full sync (h0 frags + LDS weights)
  GATE_MFMA(0, 0, 0, pgf0, pgf1, ;);   // pgf01 for step 0

  int p = 0;
  for (int ts = 0; ts < T_; ++ts) {
    char* bf1n = BF1s[p ^ 1];
    char* bf2n = BF2s[p ^ 1];
    if (t >= 768 && ts + 1 < T_) write_u(p ^ 1);   // u(ts+1) from prefetch regs

    // ---- phase A: pp=1 MFMAs(ts); combine + ACT(0/1) in the latency shadow ----
    {
      unsigned bf1pk, bf2pk;
      float4v pg2, pg3;
      GATE_MFMA(p, p, 1, pg2, pg3,
        if (ts) {   // combine: zp(ts) = zp(ts-1) + delta(ts-1); out[ts-1]
          float4 ps = ((const float4*)pslot)[bcol];
          float delta = fmaxf((ps.x + ps.y) + (ps.z + ps.w) + b2v, 0.f);
          zp_r += delta;
          if (wid == 4 && l < 16) out[(b0 + l) * T_ + ts - 1] = zp_r;
        }
        ACT(0, pgf0);
        ACT(1, pgf1);
      );
      ACT(2, pg2);
      ACT(3, pg3);
      // packed h-frag stores: one b32 per i8 buffer, one b64 for bf16
      *(unsigned*)&bf1n[(wid * 16 + bcol) * 16 + lk * 4] = bf1pk;
      *(unsigned*)&bf2n[(wid * 16 + bcol) * 16 + lk * 4] = bf2pk;
      uint2 hv;
      hv.x = bf16rne(h_r[0]) | (bf16rne(h_r[1]) << 16);
      hv.y = bf16rne(h_r[2]) | (bf16rne(h_r[3]) << 16);
      int hbase = ((wid >> 1) * 64 + ((wid & 1) * 2 + (lk >> 1)) * 16 + bcol) * 8
                + (lk & 1) * 4;
      *(uint2*)&HBs[hbase] = hv;
    }
    BAR();             // (1) h(ts) frags + u(ts+1) visible; vmem stays in flight

    // ---- phase B: pp=0 MFMAs(ts+1) || FF(ts) || u(ts+2) prefetch ----
    if (t >= 768 && ts + 2 < T_) load_u(ts + 2);   // in flight across BAR2
    if (ts + 1 < T_) { GATE_MFMA(p ^ 1, p ^ 1, 0, pgf0, pgf1, ;); }
    if (wid < 4) {
      __builtin_amdgcn_s_setprio(1);               // FF waves are the laggard
      float4v fa0 = (float4v){0.f,0.f,0.f,0.f}, fa1 = (float4v){0.f,0.f,0.f,0.f};
      const short* w1s = (const short*)W1ls;
      #pragma unroll
      for (int kt = 0; kt < 4; ++kt) {   // two independent 4-deep chains
        short8 bfA = *(const short8*)&HBs[((2*kt)   * 64 + l) * 8];
        short8 wfA = *(const short8*)&w1s[((wid * 8 + 2*kt)   * 64 + l) * 8];
        fa0 = __builtin_amdgcn_mfma_f32_16x16x32_bf16(wfA, bfA, fa0, 0, 0, 0);
        short8 bfB = *(const short8*)&HBs[((2*kt+1) * 64 + l) * 8];
        short8 wfB = *(const short8*)&w1s[((wid * 8 + 2*kt+1) * 64 + l) * 8];
        fa1 = __builtin_amdgcn_mfma_f32_16x16x32_bf16(wfB, bfB, fa1, 0, 0, 0);
      }
      float s = 0.f;
      #pragma unroll
      for (int r = 0; r < 4; ++r) {
        int j = wid * 16 + lk * 4 + r;
        s = fmaf(w2_lds[j], fmaxf(fa0[r] + fa1[r] + b1_lds[j], 0.f), s);
      }
      s += __shfl_xor(s, 16);          // reduce over lk (same bcol)
      s += __shfl_xor(s, 32);
      if (l < 16) pslot[l * 4 + wid] = s;   // transposed: [batch][wave]
      __builtin_amdgcn_s_setprio(0);
    }
    BAR();             // (2) pslot ready; prefetch loads stay in flight
    p ^= 1;
  }

  // ---- epilogue: final combine + out[T-1], then h/c outputs ----
  {
    float4 ps = ((const float4*)pslot)[bcol];
    float delta = fmaxf((ps.x + ps.y) + (ps.z + ps.w) + b2v, 0.f);
    zp_r += delta;
    if (wid == 4 && l < 16) out[(b0 + l) * T_ + T_ - 1] = zp_r;
  }
  #pragma unroll
  for (int i = 0; i < 4; ++i) {
    int d = wid * 16 + lk * 4 + i;
    out[B_ * T_ + (b0 + bcol) * H_ + d]            = h_r[i];
    out[B_ * T_ + B_ * H_ + (b0 + bcol) * H_ + d]  = c_r[i];
  }
}

extern "C" void kernel_launch(void* const* d_in, const int* in_sizes, int n_in,
                              void* d_out, int out_size, void* d_ws, size_t ws_size,
                              hipStream_t stream) {
  const float* z   = (const float*)d_in[0];
  const float* x   = (const float*)d_in[1];
  const float* h0  = (const float*)d_in[2];
  const float* Wih = (const float*)d_in[3];
  const float* Whh = (const float*)d_in[4];
  const float* b   = (const float*)d_in[5];
  const float* W1  = (const float*)d_in[6];
  const float* b1  = (const float*)d_in[7];
  const float* W2  = (const float*)d_in[8];
  const float* b2  = (const float*)d_in[9];
  float* out = (float*)d_out;

  char* ws = (char*)d_ws;
  uint4* PA8   = (uint4*)(ws);             // 16384*16 = 262144 B
  uint4* W1Pg  = (uint4*)(ws + 262144);    //  2048*16 =  32768 B
  uint4* WU    = (uint4*)(ws + 294912);    //  4096*16 =  65536 B
  float* SCL4  = (float*)(ws + 360448);    //  1024*4  =   4096 B
  float* Mraw  = (float*)(ws + 364544);    //  1024*4  =   4096 B
  float* WIH17 = (float*)(ws + 368640);    //  1024*4  =   4096 B

  pack_scales<<<1024, 256, 0, stream>>>(Whh, Wih, Mraw, SCL4, WIH17);
  int total = 16384 + 2048 + 4096;
  pack_frags<<<(total + 255) / 256, 256, 0, stream>>>(Wih, Whh, b, W1, Mraw,
                                                      PA8, W1Pg, WU);
  lstm_kernel<<<NBLK, 1024, 0, stream>>>(z, x, h0, (const int4v*)PA8, (const uint4*)WU,
                                         W1Pg, SCL4, WIH17, b1, W2, b2, out);
}